// Round 7
// baseline (281.433 us; speedup 1.0000x reference)
//
#include <hip/hip_runtime.h>
#include <cstdint>
#include <cstddef>

// Problem shape (fixed by setup_inputs): B=8, W=1024, H=8, D=64
#define W  1024
#define NH 8
#define NB 8
#define DH 64
#define BHN (NB*NH)                      // 64 batch-heads
#define CTX_ELEMS ((size_t)NB*W*NH*DH)   // 4194304
#define NS 64                            // atomic spread width
#define ROWF 512                         // row stride in floats (NH*DH)
#define L2E 1.4426950408889634f

typedef int v4i __attribute__((ext_vector_type(4)));

// ---------- helpers ----------

__device__ __forceinline__ unsigned enc_f(float f){
  unsigned u = __float_as_uint(f);
  return (u & 0x80000000u) ? ~u : (u | 0x80000000u);
}
__device__ __forceinline__ float dec_f(unsigned k){
  unsigned u = (k & 0x80000000u) ? (k ^ 0x80000000u) : ~k;
  return __uint_as_float(u);
}

// exact-division fake-quant (final ctx quant — matches reference bitwise)
__device__ __forceinline__ float fq1(float x, float s, float z, float mn, float mx){
  float t = rintf(x / s) + z;
  t = fminf(fmaxf(t, mn), mx);
  return (t - z) * s;
}
// reciprocal-multiply quantize to integer level (hot paths)
__device__ __forceinline__ int qint_m(float x, float is, float z, float mn, float mx){
  return (int)fminf(fmaxf(rintf(x * is) + z, mn), mx);
}
__device__ __forceinline__ unsigned pack4(int a0, int a1, int a2, int a3){
  return (unsigned)(a0 & 0xff) | ((unsigned)(a1 & 0xff) << 8) |
         ((unsigned)(a2 & 0xff) << 16) | ((unsigned)(a3 & 0xff) << 24);
}

__device__ __forceinline__ unsigned* slot_min(unsigned* s, int t){ return s + (size_t)(2*t)*NS; }
__device__ __forceinline__ unsigned* slot_max(unsigned* s, int t){ return s + (size_t)(2*t+1)*NS; }

struct QP { float s, z; };

// per-block re-derivation of qparams from spread slots (identical arithmetic everywhere)
__device__ __forceinline__ QP qp_generic(const unsigned* slots, int t, float qmn, float qmx){
  const unsigned* pm = slots + (size_t)(2*t)*NS;
  const unsigned* px = pm + NS;
  unsigned em = pm[0], ex = px[0];
  for (int i = 1; i < NS; ++i){
    unsigned a = pm[i], b = px[i];
    em = (a < em) ? a : em;
    ex = (b > ex) ? b : ex;
  }
  float mn = dec_f(em), mx = dec_f(ex);
  QP r;
  r.s = fmaxf((mx - mn) / (qmx - qmn), 1e-8f);
  r.z = fminf(fmaxf(rintf(qmn - mn / r.s), qmn), qmx);
  return r;
}
__device__ __forceinline__ QP qp_scores(const int* jmn, const int* jmx, float sq, float sk,
                                        float qmn, float qmx){
  int em = jmn[0], ex = jmx[0];
  for (int i = 1; i < NS; ++i){ em = min(em, jmn[i]); ex = max(ex, jmx[i]); }
  float cfac = 0.125f * (sq * sk);
  float mn = fminf(cfac * (float)em, 0.0f);
  float mx = fmaxf(cfac * (float)ex, 0.0f);
  QP r;
  r.s = fmaxf((mx - mn) / (qmx - qmn), 1e-8f);
  r.z = fminf(fmaxf(rintf(qmn - mn / r.s), qmn), qmx);
  return r;
}

__device__ __forceinline__ void blk_minmax_atomic(float lmin, float lmax,
                                                  unsigned* smin, unsigned* smax){
  #pragma unroll
  for (int o = 32; o; o >>= 1){
    lmin = fminf(lmin, __shfl_xor(lmin, o));
    lmax = fmaxf(lmax, __shfl_xor(lmax, o));
  }
  __shared__ float wmn[4], wmx[4];
  int wid = threadIdx.x >> 6, lane = threadIdx.x & 63;
  if (lane == 0){ wmn[wid] = lmin; wmx[wid] = lmax; }
  __syncthreads();
  if (threadIdx.x == 0){
    float a = wmn[0], b = wmx[0];
    for (int w = 1; w < (int)(blockDim.x >> 6); ++w){
      a = fminf(a, wmn[w]); b = fmaxf(b, wmx[w]);
    }
    atomicMin(smin, enc_f(a));
    atomicMax(smax, enc_f(b));
  }
}

__device__ __forceinline__ void blk_iminmax_atomic(int lmin, int lmax, int* gmin, int* gmax){
  #pragma unroll
  for (int o = 32; o; o >>= 1){
    lmin = min(lmin, __shfl_xor(lmin, o));
    lmax = max(lmax, __shfl_xor(lmax, o));
  }
  __shared__ int iwmn[4], iwmx[4];
  int wid = threadIdx.x >> 6, lane = threadIdx.x & 63;
  if (lane == 0){ iwmn[wid] = lmin; iwmx[wid] = lmax; }
  __syncthreads();
  if (threadIdx.x == 0){
    int a = iwmn[0], b = iwmx[0];
    for (int w = 1; w < (int)(blockDim.x >> 6); ++w){
      a = min(a, iwmn[w]); b = max(b, iwmx[w]);
    }
    atomicMin(gmin, a);
    atomicMax(gmax, b);
  }
}

// stage a 64-row x 64-d fp32 tile -> int8 LDS [row][d] (+row sums via 4-lane shfl)
__device__ __forceinline__ void stage_tile(const float* __restrict__ rowptr,
                                           signed char (*S)[80], int* __restrict__ Ssum,
                                           float is, float z, float mn, float mx, int t){
  const int rr = t >> 2, dq = (t & 3) << 4;
  const float* p = rowptr + (size_t)rr * ROWF + dq;
  int part = 0;
  #pragma unroll
  for (int g = 0; g < 4; ++g){
    float4 x = *(const float4*)(p + g * 4);
    int a0 = qint_m(x.x, is, z, mn, mx), a1 = qint_m(x.y, is, z, mn, mx);
    int a2 = qint_m(x.z, is, z, mn, mx), a3 = qint_m(x.w, is, z, mn, mx);
    part += a0 + a1 + a2 + a3;
    *(unsigned*)&S[rr][dq + g*4] = pack4(a0, a1, a2, a3);
  }
  int x1 = part + __shfl_xor(part, 1);
  int tot = x1 + __shfl_xor(x1, 2);
  if ((t & 3) == 0) Ssum[rr] = tot;
}

// ---------- kernels ----------

__global__ void init_slots_kernel(unsigned* __restrict__ slots, int* __restrict__ jmn,
                                  int* __restrict__ jmx){
  for (int i = threadIdx.x; i < 6*2*NS; i += blockDim.x)
    slots[i] = 0x80000000u;   // enc(0.0f): reference clamps min<=0<=max
  if (threadIdx.x < NS){
    jmn[threadIdx.x] = 0x7fffffff;
    jmx[threadIdx.x] = (int)0x80000000;
  }
}

__global__ __launch_bounds__(256) void minmax3_kernel(const float* __restrict__ q,
                                                      const float* __restrict__ k,
                                                      const float* __restrict__ v,
                                                      unsigned* __restrict__ slots){
  const float4* p = (const float4*)(blockIdx.y == 0 ? q : (blockIdx.y == 1 ? k : v));
  float lmin = 0.f, lmax = 0.f;
  const int n4 = (int)(CTX_ELEMS / 4);
  for (int i = blockIdx.x * blockDim.x + threadIdx.x; i < n4; i += gridDim.x * blockDim.x){
    float4 x = p[i];
    lmin = fminf(lmin, fminf(fminf(x.x, x.y), fminf(x.z, x.w)));
    lmax = fmaxf(lmax, fmaxf(fmaxf(x.x, x.y), fmaxf(x.z, x.w)));
  }
  const int idx = blockIdx.x & (NS - 1);
  blk_minmax_atomic(lmin, lmax, slot_min(slots, blockIdx.y) + idx, slot_max(slots, blockIdx.y) + idx);
}

// pass1: swapped-operand QK MFMA; global J min/max + per-row Jmax -> ctx stash d=0.
__global__ __launch_bounds__(256) void pass1_kernel(const float* __restrict__ qg,
                                                    const float* __restrict__ kg,
                                                    const unsigned* __restrict__ slots,
                                                    const int* __restrict__ bits_p,
                                                    float* __restrict__ stash,
                                                    int* __restrict__ jmn,
                                                    int* __restrict__ jmx){
  __shared__ __align__(16) signed char Qs[64][80], Ks[64][80];
  __shared__ int Sq[64], Sk[64];
  const int bits = *bits_p;
  const float qmx = (float)((1 << (bits-1)) - 1), qmn = -(float)(1 << (bits-1));
  const QP qq = qp_generic(slots, 0, qmn, qmx);
  const QP kp = qp_generic(slots, 1, qmn, qmx);
  const int it = blockIdx.x, bh = blockIdx.y, b = bh >> 3, h = bh & 7;
  const int i0 = it << 6, t = threadIdx.x;
  const int lane = t & 63, w = t >> 6, lr = lane & 15, lg = lane >> 4;
  const float isq = 1.0f / qq.s, isk = 1.0f / kp.s;
  const int izq = (int)qq.z, izk = (int)kp.z, c64 = 64 * izq * izk;

  stage_tile(qg + ((size_t)(b*W + i0) * NH + h) * DH, Qs, Sq, isq, qq.z, qmn, qmx, t);
  __syncthreads();
  const v4i Bq = *(const v4i*)&Qs[(w << 4) + lr][lg << 4];
  const int sqi = Sq[(w << 4) + lr];

  int gmin = 0x7fffffff, gmax = (int)0x80000000, rmax = (int)0x80000000;
  for (int cc = 0; cc < 16; ++cc){
    __syncthreads();
    stage_tile(kg + ((size_t)(b*W + (cc << 6)) * NH + h) * DH, Ks, Sk, isk, kp.z, qmn, qmx, t);
    __syncthreads();
    #pragma unroll
    for (int jt = 0; jt < 4; ++jt){
      v4i Ak = *(const v4i*)&Ks[(jt << 4) + lr][lg << 4];
      v4i zz = {0, 0, 0, 0};
      v4i acc = __builtin_amdgcn_mfma_i32_16x16x64_i8(Ak, Bq, zz, 0, 0, 0);
      v4i s4 = *(const v4i*)&Sk[(jt << 4) + (lg << 2)];
      #pragma unroll
      for (int r = 0; r < 4; ++r){
        int J = acc[r] - izq * s4[r] - izk * sqi + c64;
        gmin = min(gmin, J); gmax = max(gmax, J); rmax = max(rmax, J);
      }
    }
  }
  rmax = max(rmax, __shfl_xor(rmax, 16));
  rmax = max(rmax, __shfl_xor(rmax, 32));
  if (lg == 0)
    stash[((size_t)(b*W + i0 + (w << 4) + lr) * NH + h) * DH] = __int_as_float(rmax);
  const int idx = (it + bh * 16) & (NS - 1);
  blk_iminmax_atomic(gmin, gmax, jmn + idx, jmx + idx);
}

// pass2: per-row Z via exp2 (-> stash d=1); t-levels packed into att (16 dwords per
// 64-float chunk, slot s = lg*4+jt); global att max (=max 1/Z) -> slot 4.
__global__ __launch_bounds__(256) void pass2_kernel(const float* __restrict__ qg,
                                                    const float* __restrict__ kg,
                                                    unsigned* __restrict__ slots,
                                                    const int* __restrict__ jmn,
                                                    const int* __restrict__ jmx,
                                                    const int* __restrict__ bits_p,
                                                    float* __restrict__ att,
                                                    float* __restrict__ stash){
  __shared__ __align__(16) signed char Qs[64][80], Ks[64][80];
  __shared__ int Sq[64], Sk[64];
  const int bits = *bits_p;
  const float qmx = (float)((1 << (bits-1)) - 1), qmn = -(float)(1 << (bits-1));
  const QP qq = qp_generic(slots, 0, qmn, qmx);
  const QP kp = qp_generic(slots, 1, qmn, qmx);
  const QP sp = qp_scores(jmn, jmx, qq.s, kp.s, qmn, qmx);
  const int it = blockIdx.x, bh = blockIdx.y, b = bh >> 3, h = bh & 7;
  const int i0 = it << 6, t = threadIdx.x;
  const int lane = t & 63, w = t >> 6, lr = lane & 15, lg = lane >> 4;
  const float isq = 1.0f / qq.s, isk = 1.0f / kp.s;
  const int izq = (int)qq.z, izk = (int)kp.z, c64 = 64 * izq * izk;
  const float rf = (0.125f * (qq.s * kp.s)) / sp.s;
  const float c2 = sp.s * L2E;
  const float zs = sp.z;

  stage_tile(qg + ((size_t)(b*W + i0) * NH + h) * DH, Qs, Sq, isq, qq.z, qmn, qmx, t);
  __syncthreads();
  const v4i Bq = *(const v4i*)&Qs[(w << 4) + lr][lg << 4];
  const int sqi = Sq[(w << 4) + lr];
  const int irow = (w << 4) + lr;
  int Jm = __float_as_int(stash[((size_t)(b*W + i0 + irow) * NH + h) * DH]);
  const float tmxf = fminf(fmaxf(rintf((float)Jm * rf) + zs, qmn), qmx);
  const size_t rowbase = ((size_t)bh << 20) + ((size_t)(i0 + irow) << 10);

  float zacc = 0.f;
  for (int cc = 0; cc < 16; ++cc){
    __syncthreads();
    stage_tile(kg + ((size_t)(b*W + (cc << 6)) * NH + h) * DH, Ks, Sk, isk, kp.z, qmn, qmx, t);
    __syncthreads();
    #pragma unroll
    for (int jt = 0; jt < 4; ++jt){
      v4i Ak = *(const v4i*)&Ks[(jt << 4) + lr][lg << 4];
      v4i zz = {0, 0, 0, 0};
      v4i acc = __builtin_amdgcn_mfma_i32_16x16x64_i8(Ak, Bq, zz, 0, 0, 0);
      v4i s4 = *(const v4i*)&Sk[(jt << 4) + (lg << 2)];
      int J0 = acc[0] - izq * s4[0] - izk * sqi + c64;
      int J1 = acc[1] - izq * s4[1] - izk * sqi + c64;
      int J2 = acc[2] - izq * s4[2] - izk * sqi + c64;
      int J3 = acc[3] - izq * s4[3] - izk * sqi + c64;
      float tl0 = fminf(fmaxf(rintf((float)J0 * rf) + zs, qmn), qmx);
      float tl1 = fminf(fmaxf(rintf((float)J1 * rf) + zs, qmn), qmx);
      float tl2 = fminf(fmaxf(rintf((float)J2 * rf) + zs, qmn), qmx);
      float tl3 = fminf(fmaxf(rintf((float)J3 * rf) + zs, qmn), qmx);
      zacc += exp2f((tl0 - tmxf) * c2);
      zacc += exp2f((tl1 - tmxf) * c2);
      zacc += exp2f((tl2 - tmxf) * c2);
      zacc += exp2f((tl3 - tmxf) * c2);
      // t8 store: dword slot s = lg*4 + jt inside this row's cc-chunk (first 16 floats)
      att[rowbase + (cc << 6) + (lg << 2) + jt] =
        __uint_as_float(pack4((int)tl0, (int)tl1, (int)tl2, (int)tl3));
    }
  }
  zacc += __shfl_xor(zacc, 16);
  zacc += __shfl_xor(zacc, 32);
  if (lg == 0)
    stash[((size_t)(b*W + i0 + irow) * NH + h) * DH + 1] = zacc;
  float ratt = 1.0f / zacc;            // row max of softmax = exp2(0)/Z = 1/Z exactly
  #pragma unroll
  for (int o = 1; o < 16; o <<= 1) ratt = fmaxf(ratt, __shfl_xor(ratt, o));
  if (lane == 0){
    const int idx = ((it << 2) + w + bh * 64) & (NS - 1);
    atomicMax(slot_max(slots, 4) + idx, enc_f(ratt));
  }
}

// pass3: read t8 from att (no QK recompute), transform -> att_q (float4, overwrites own
// t8 dwords only) + int8 PV-MFMA -> raw ctx + ctx minmax -> slot 5.
__global__ __launch_bounds__(256) void pass3_kernel(const float* __restrict__ vg,
                                                    float* __restrict__ att,
                                                    float* __restrict__ ctx,
                                                    unsigned* __restrict__ slots,
                                                    const int* __restrict__ jmn,
                                                    const int* __restrict__ jmx,
                                                    const int* __restrict__ bits_p){
  __shared__ __align__(16) signed char Vs[64][80], As[64][80];
  __shared__ int RowA[64], ColV[64];
  const int bits = *bits_p;
  const float qmx = (float)((1 << (bits-1)) - 1), qmn = -(float)(1 << (bits-1));
  const QP qq = qp_generic(slots, 0, qmn, qmx);
  const QP kp = qp_generic(slots, 1, qmn, qmx);
  const QP sp = qp_scores(jmn, jmx, qq.s, kp.s, qmn, qmx);
  const QP vp = qp_generic(slots, 2, qmn, qmx);
  const QP ap = qp_generic(slots, 4, qmn, qmx);
  const int it = blockIdx.x, bh = blockIdx.y, b = bh >> 3, h = bh & 7;
  const int i0 = it << 6, t = threadIdx.x;
  const int lane = t & 63, w = t >> 6, lr = lane & 15, lg = lane >> 4;
  const float rf = (0.125f * (qq.s * kp.s)) / sp.s;
  const float c2 = sp.s * L2E, zs = sp.z;
  const float sa = ap.s, za = ap.z, inv_sa = 1.0f / sa;
  const float sv = vp.s, zv = vp.z, isv = 1.0f / sv;
  const int iza = (int)za, izv = (int)zv;

  if (t < 64) ColV[t] = 0;
  const int irow = (w << 4) + lr;
  const size_t rbase = ((size_t)(b*W + i0 + irow) * NH + h) * DH;
  int Jm = __float_as_int(ctx[rbase]);
  const float tmxf = fminf(fmaxf(rintf((float)Jm * rf) + zs, qmn), qmx);
  const float iZ = 1.0f / ctx[rbase + 1];
  const size_t rowbase = ((size_t)bh << 20) + ((size_t)(i0 + irow) << 10);

  const int dq4 = (t & 15) << 2;       // V: 4 d's per thread
  const int kb  = (t >> 4) << 2;       // V: 4 kk's per thread
  int cv4[4] = {0, 0, 0, 0};
  int rA = 0;
  v4i accPV[4];
  #pragma unroll
  for (int tj = 0; tj < 4; ++tj){ v4i zz = {0,0,0,0}; accPV[tj] = zz; }

  for (int cc = 0; cc < 16; ++cc){
    __syncthreads();
    {
      const float* vp_ = vg + ((size_t)(b*W + (cc << 6) + kb) * NH + h) * DH + dq4;
      float4 x0 = *(const float4*)(vp_);
      float4 x1 = *(const float4*)(vp_ + ROWF);
      float4 x2 = *(const float4*)(vp_ + 2 * ROWF);
      float4 x3 = *(const float4*)(vp_ + 3 * ROWF);
      int q00 = qint_m(x0.x, isv, zv, qmn, qmx), q01 = qint_m(x0.y, isv, zv, qmn, qmx),
          q02 = qint_m(x0.z, isv, zv, qmn, qmx), q03 = qint_m(x0.w, isv, zv, qmn, qmx);
      int q10 = qint_m(x1.x, isv, zv, qmn, qmx), q11 = qint_m(x1.y, isv, zv, qmn, qmx),
          q12 = qint_m(x1.z, isv, zv, qmn, qmx), q13 = qint_m(x1.w, isv, zv, qmn, qmx);
      int q20 = qint_m(x2.x, isv, zv, qmn, qmx), q21 = qint_m(x2.y, isv, zv, qmn, qmx),
          q22 = qint_m(x2.z, isv, zv, qmn, qmx), q23 = qint_m(x2.w, isv, zv, qmn, qmx);
      int q30 = qint_m(x3.x, isv, zv, qmn, qmx), q31 = qint_m(x3.y, isv, zv, qmn, qmx),
          q32 = qint_m(x3.z, isv, zv, qmn, qmx), q33 = qint_m(x3.w, isv, zv, qmn, qmx);
      cv4[0] += q00 + q10 + q20 + q30;
      cv4[1] += q01 + q11 + q21 + q31;
      cv4[2] += q02 + q12 + q22 + q32;
      cv4[3] += q03 + q13 + q23 + q33;
      *(unsigned*)&Vs[dq4 + 0][kb] = pack4(q00, q10, q20, q30);
      *(unsigned*)&Vs[dq4 + 1][kb] = pack4(q01, q11, q21, q31);
      *(unsigned*)&Vs[dq4 + 2][kb] = pack4(q02, q12, q22, q32);
      *(unsigned*)&Vs[dq4 + 3][kb] = pack4(q03, q13, q23, q33);
    }
    __syncthreads();

    // t8 load: 4 dwords (slots lg*4 .. lg*4+3) = one float4; these exact floats are
    // the ONLY t8 this lane's att stores clobber (self-clobber after load — safe).
    const size_t cb = rowbase + ((size_t)cc << 6);
    float4 tf = *(const float4*)(att + cb + (lg << 2));
    unsigned uu[4] = { __float_as_uint(tf.x), __float_as_uint(tf.y),
                       __float_as_uint(tf.z), __float_as_uint(tf.w) };
    #pragma unroll
    for (int jt = 0; jt < 4; ++jt){
      unsigned u = uu[jt];
      float t0 = (float)(int)(signed char)(u & 0xff);
      float t1 = (float)(int)(signed char)((u >> 8) & 0xff);
      float t2 = (float)(int)(signed char)((u >> 16) & 0xff);
      float t3 = (float)(int)(signed char)((u >> 24) & 0xff);
      float p0 = exp2f((t0 - tmxf) * c2) * iZ;
      float p1 = exp2f((t1 - tmxf) * c2) * iZ;
      float p2 = exp2f((t2 - tmxf) * c2) * iZ;
      float p3 = exp2f((t3 - tmxf) * c2) * iZ;
      float a0 = fminf(fmaxf(rintf(p0 * inv_sa) + za, qmn), qmx);
      float a1 = fminf(fmaxf(rintf(p1 * inv_sa) + za, qmn), qmx);
      float a2 = fminf(fmaxf(rintf(p2 * inv_sa) + za, qmn), qmx);
      float a3 = fminf(fmaxf(rintf(p3 * inv_sa) + za, qmn), qmx);
      float4 y;
      y.x = (a0 - za) * sa; y.y = (a1 - za) * sa;
      y.z = (a2 - za) * sa; y.w = (a3 - za) * sa;
      *(float4*)(att + cb + (jt << 4) + (lg << 2)) = y;
      int q0 = (int)a0, q1 = (int)a1, q2 = (int)a2, q3 = (int)a3;
      rA += q0 + q1 + q2 + q3;
      *(unsigned*)&As[irow][(jt << 4) + (lg << 2)] = pack4(q0, q1, q2, q3);
    }
    // As rows of this wave written only by this wave; LDS ops in-order -> no barrier
    {
      v4i A2 = *(const v4i*)&As[(w << 4) + lr][lg << 4];
      #pragma unroll
      for (int tj = 0; tj < 4; ++tj){
        v4i B2 = *(const v4i*)&Vs[(tj << 4) + lr][lg << 4];
        accPV[tj] = __builtin_amdgcn_mfma_i32_16x16x64_i8(A2, B2, accPV[tj], 0, 0, 0);
      }
    }
  }

  rA += __shfl_xor(rA, 16);
  rA += __shfl_xor(rA, 32);
  if (lg == 0) RowA[irow] = rA;
  #pragma unroll
  for (int j = 0; j < 4; ++j) atomicAdd(&ColV[dq4 + j], cv4[j]);
  __syncthreads();

  const float sav = sa * sv;
  float lmin = 0.f, lmax = 0.f;
  #pragma unroll
  for (int tj = 0; tj < 4; ++tj){
    const int d = (tj << 4) + lr;
    #pragma unroll
    for (int r = 0; r < 4; ++r){
      const int i = (w << 4) + (lg << 2) + r;
      int Jv = accPV[tj][r] - iza * ColV[d] - izv * RowA[i] + 1024 * iza * izv;
      float c = sav * (float)Jv;
      lmin = fminf(lmin, c); lmax = fmaxf(lmax, c);
      ctx[(((size_t)(b * W + i0 + i)) * NH + h) * DH + d] = c;
    }
  }
  const int idx = (it + bh * 16) & (NS - 1);
  blk_minmax_atomic(lmin, lmax, slot_min(slots, 5) + idx, slot_max(slots, 5) + idx);
}

__global__ __launch_bounds__(256) void quantctx_kernel(float* __restrict__ ctx,
                                                       const unsigned* __restrict__ slots,
                                                       const int* __restrict__ bits_p){
  const int bits = *bits_p;
  const float qmx = (float)((1 << (bits-1)) - 1), qmn = -(float)(1 << (bits-1));
  const QP cp = qp_generic(slots, 5, qmn, qmx);
  size_t i = (size_t)blockIdx.x * blockDim.x + threadIdx.x;   // float4 index
  float4* p = (float4*)ctx;
  float4 x = p[i];
  x.x = fq1(x.x, cp.s, cp.z, qmn, qmx);
  x.y = fq1(x.y, cp.s, cp.z, qmn, qmx);
  x.z = fq1(x.z, cp.s, cp.z, qmn, qmx);
  x.w = fq1(x.w, cp.s, cp.z, qmn, qmx);
  p[i] = x;
}

// ---------- launch ----------

extern "C" void kernel_launch(void* const* d_in, const int* in_sizes, int n_in,
                              void* d_out, int out_size, void* d_ws, size_t ws_size,
                              hipStream_t stream){
  const float* q = (const float*)d_in[0];
  const float* k = (const float*)d_in[1];
  const float* v = (const float*)d_in[2];
  const int* bits = (const int*)d_in[3];
  float* ctx = (float*)d_out;                      // hosts per-row {Jmax,Z} stash (d=0,1)
  float* att = (float*)d_out + CTX_ELEMS;          // t8 (pass2) -> att_q (pass3, in place)
  unsigned* slots = (unsigned*)d_ws;               // 768 uints (3072 B)
  int* jmn = (int*)((char*)d_ws + 3072);           // 64 ints
  int* jmx = (int*)((char*)d_ws + 3328);           // 64 ints

  hipLaunchKernelGGL(init_slots_kernel, dim3(1), dim3(256), 0, stream, slots, jmn, jmx);
  hipLaunchKernelGGL(minmax3_kernel, dim3(512, 3), dim3(256), 0, stream, q, k, v, slots);
  hipLaunchKernelGGL(pass1_kernel, dim3(16, BHN), dim3(256), 0, stream, q, k, slots, bits, ctx, jmn, jmx);
  hipLaunchKernelGGL(pass2_kernel, dim3(16, BHN), dim3(256), 0, stream, q, k, slots, jmn, jmx, bits, att, ctx);
  hipLaunchKernelGGL(pass3_kernel, dim3(16, BHN), dim3(256), 0, stream, v, att, ctx, slots, jmn, jmx, bits);
  hipLaunchKernelGGL(quantctx_kernel, dim3(4096), dim3(256), 0, stream, ctx, slots, bits);
}

// Round 8
// 224.534 us; speedup vs baseline: 1.2534x; 1.2534x over previous
//
#include <hip/hip_runtime.h>
#include <cstdint>
#include <cstddef>

// Problem shape (fixed by setup_inputs): B=8, W=1024, H=8, D=64
#define W  1024
#define NH 8
#define NB 8
#define DH 64
#define BHN (NB*NH)                      // 64 batch-heads
#define CTX_ELEMS ((size_t)NB*W*NH*DH)   // 4194304
#define NS 64                            // atomic spread width
#define ROWF 512                         // row stride in floats (NH*DH)
#define L2E 1.4426950408889634f

typedef int v4i __attribute__((ext_vector_type(4)));

// ---------- helpers ----------

__device__ __forceinline__ unsigned enc_f(float f){
  unsigned u = __float_as_uint(f);
  return (u & 0x80000000u) ? ~u : (u | 0x80000000u);
}
__device__ __forceinline__ float dec_f(unsigned k){
  unsigned u = (k & 0x80000000u) ? (k ^ 0x80000000u) : ~k;
  return __uint_as_float(u);
}

// exact-division fake-quant (final ctx quant — matches reference bitwise)
__device__ __forceinline__ float fq1(float x, float s, float z, float mn, float mx){
  float t = rintf(x / s) + z;
  t = fminf(fmaxf(t, mn), mx);
  return (t - z) * s;
}
// reciprocal-multiply quantize to integer level (hot paths)
__device__ __forceinline__ int qint_m(float x, float is, float z, float mn, float mx){
  return (int)fminf(fmaxf(rintf(x * is) + z, mn), mx);
}
__device__ __forceinline__ unsigned pack4(int a0, int a1, int a2, int a3){
  return (unsigned)(a0 & 0xff) | ((unsigned)(a1 & 0xff) << 8) |
         ((unsigned)(a2 & 0xff) << 16) | ((unsigned)(a3 & 0xff) << 24);
}

__device__ __forceinline__ unsigned* slot_min(unsigned* s, int t){ return s + (size_t)(2*t)*NS; }
__device__ __forceinline__ unsigned* slot_max(unsigned* s, int t){ return s + (size_t)(2*t+1)*NS; }

struct QP { float s, z; };

// per-block re-derivation of qparams from spread slots (identical arithmetic everywhere)
__device__ __forceinline__ QP qp_generic(const unsigned* slots, int t, float qmn, float qmx){
  const unsigned* pm = slots + (size_t)(2*t)*NS;
  const unsigned* px = pm + NS;
  unsigned em = pm[0], ex = px[0];
  for (int i = 1; i < NS; ++i){
    unsigned a = pm[i], b = px[i];
    em = (a < em) ? a : em;
    ex = (b > ex) ? b : ex;
  }
  float mn = dec_f(em), mx = dec_f(ex);
  QP r;
  r.s = fmaxf((mx - mn) / (qmx - qmn), 1e-8f);
  r.z = fminf(fmaxf(rintf(qmn - mn / r.s), qmn), qmx);
  return r;
}
__device__ __forceinline__ QP qp_scores(const int* jmn, const int* jmx, float sq, float sk,
                                        float qmn, float qmx){
  int em = jmn[0], ex = jmx[0];
  for (int i = 1; i < NS; ++i){ em = min(em, jmn[i]); ex = max(ex, jmx[i]); }
  float cfac = 0.125f * (sq * sk);
  float mn = fminf(cfac * (float)em, 0.0f);
  float mx = fmaxf(cfac * (float)ex, 0.0f);
  QP r;
  r.s = fmaxf((mx - mn) / (qmx - qmn), 1e-8f);
  r.z = fminf(fmaxf(rintf(qmn - mn / r.s), qmn), qmx);
  return r;
}

__device__ __forceinline__ void blk_minmax_atomic(float lmin, float lmax,
                                                  unsigned* smin, unsigned* smax){
  #pragma unroll
  for (int o = 32; o; o >>= 1){
    lmin = fminf(lmin, __shfl_xor(lmin, o));
    lmax = fmaxf(lmax, __shfl_xor(lmax, o));
  }
  __shared__ float wmn[4], wmx[4];
  int wid = threadIdx.x >> 6, lane = threadIdx.x & 63;
  if (lane == 0){ wmn[wid] = lmin; wmx[wid] = lmax; }
  __syncthreads();
  if (threadIdx.x == 0){
    float a = wmn[0], b = wmx[0];
    for (int w = 1; w < (int)(blockDim.x >> 6); ++w){
      a = fminf(a, wmn[w]); b = fmaxf(b, wmx[w]);
    }
    atomicMin(smin, enc_f(a));
    atomicMax(smax, enc_f(b));
  }
}

__device__ __forceinline__ void blk_iminmax_atomic(int lmin, int lmax, int* gmin, int* gmax){
  #pragma unroll
  for (int o = 32; o; o >>= 1){
    lmin = min(lmin, __shfl_xor(lmin, o));
    lmax = max(lmax, __shfl_xor(lmax, o));
  }
  __shared__ int iwmn[4], iwmx[4];
  int wid = threadIdx.x >> 6, lane = threadIdx.x & 63;
  if (lane == 0){ iwmn[wid] = lmin; iwmx[wid] = lmax; }
  __syncthreads();
  if (threadIdx.x == 0){
    int a = iwmn[0], b = iwmx[0];
    for (int w = 1; w < (int)(blockDim.x >> 6); ++w){
      a = min(a, iwmn[w]); b = max(b, iwmx[w]);
    }
    atomicMin(gmin, a);
    atomicMax(gmax, b);
  }
}

// stage a 64-row x 64-d fp32 tile -> int8 LDS [row][d] (+row sums via 4-lane shfl)
__device__ __forceinline__ void stage_tile(const float* __restrict__ rowptr,
                                           signed char (*S)[80], int* __restrict__ Ssum,
                                           float is, float z, float mn, float mx, int t){
  const int rr = t >> 2, dq = (t & 3) << 4;
  const float* p = rowptr + (size_t)rr * ROWF + dq;
  int part = 0;
  #pragma unroll
  for (int g = 0; g < 4; ++g){
    float4 x = *(const float4*)(p + g * 4);
    int a0 = qint_m(x.x, is, z, mn, mx), a1 = qint_m(x.y, is, z, mn, mx);
    int a2 = qint_m(x.z, is, z, mn, mx), a3 = qint_m(x.w, is, z, mn, mx);
    part += a0 + a1 + a2 + a3;
    *(unsigned*)&S[rr][dq + g*4] = pack4(a0, a1, a2, a3);
  }
  int x1 = part + __shfl_xor(part, 1);
  int tot = x1 + __shfl_xor(x1, 2);
  if ((t & 3) == 0) Ssum[rr] = tot;
}

// copy a cached int8 64x64 chunk (blob) -> LDS [row][80-padded] + sums
__device__ __forceinline__ void copy_tile(const char* __restrict__ blob8, const int* __restrict__ Ssum8,
                                          signed char (*S)[80], int* __restrict__ Ssum, int t){
  const int rr = t >> 2, p4 = (t & 3) << 4;
  *(float4*)&S[rr][p4] = *(const float4*)(blob8 + ((size_t)rr << 6) + p4);
  if (t < 64) Ssum[t] = Ssum8[t];
}

// ---------- kernels ----------

__global__ void init_slots_kernel(unsigned* __restrict__ slots, int* __restrict__ jmn,
                                  int* __restrict__ jmx){
  for (int i = threadIdx.x; i < 6*2*NS; i += blockDim.x)
    slots[i] = 0x80000000u;   // enc(0.0f): reference clamps min<=0<=max
  if (threadIdx.x < NS){
    jmn[threadIdx.x] = 0x7fffffff;
    jmx[threadIdx.x] = (int)0x80000000;
  }
}

__global__ __launch_bounds__(256) void minmax3_kernel(const float* __restrict__ q,
                                                      const float* __restrict__ k,
                                                      const float* __restrict__ v,
                                                      unsigned* __restrict__ slots){
  const float4* p = (const float4*)(blockIdx.y == 0 ? q : (blockIdx.y == 1 ? k : v));
  float lmin = 0.f, lmax = 0.f;
  const int n4 = (int)(CTX_ELEMS / 4);
  for (int i = blockIdx.x * blockDim.x + threadIdx.x; i < n4; i += gridDim.x * blockDim.x){
    float4 x = p[i];
    lmin = fminf(lmin, fminf(fminf(x.x, x.y), fminf(x.z, x.w)));
    lmax = fmaxf(lmax, fmaxf(fmaxf(x.x, x.y), fmaxf(x.z, x.w)));
  }
  const int idx = blockIdx.x & (NS - 1);
  blk_minmax_atomic(lmin, lmax, slot_min(slots, blockIdx.y) + idx, slot_max(slots, blockIdx.y) + idx);
}

// pass1: swapped-operand QK MFMA; global J min/max + per-row Jmax -> ctx stash d=0.
// If CACHED: persist quantized int8 Q/K tiles (+row sums) to ws blobs for pass2/pass3.
template<bool CACHED>
__global__ __launch_bounds__(256) void pass1_kernel(const float* __restrict__ qg,
                                                    const float* __restrict__ kg,
                                                    const unsigned* __restrict__ slots,
                                                    const int* __restrict__ bits_p,
                                                    float* __restrict__ stash,
                                                    int* __restrict__ jmn,
                                                    int* __restrict__ jmx,
                                                    char* __restrict__ q8,
                                                    char* __restrict__ k8,
                                                    int* __restrict__ Sq8,
                                                    int* __restrict__ Sk8){
  __shared__ __align__(16) signed char Qs[64][80], Ks[64][80];
  __shared__ int Sq[64], Sk[64];
  const int bits = *bits_p;
  const float qmx = (float)((1 << (bits-1)) - 1), qmn = -(float)(1 << (bits-1));
  const QP qq = qp_generic(slots, 0, qmn, qmx);
  const QP kp = qp_generic(slots, 1, qmn, qmx);
  const int it = blockIdx.x, bh = blockIdx.y, b = bh >> 3, h = bh & 7;
  const int i0 = it << 6, t = threadIdx.x;
  const int lane = t & 63, w = t >> 6, lr = lane & 15, lg = lane >> 4;
  const float isq = 1.0f / qq.s, isk = 1.0f / kp.s;
  const int izq = (int)qq.z, izk = (int)kp.z, c64 = 64 * izq * izk;

  stage_tile(qg + ((size_t)(b*W + i0) * NH + h) * DH, Qs, Sq, isq, qq.z, qmn, qmx, t);
  __syncthreads();
  if (CACHED){
    const int rr = t >> 2, p4 = (t & 3) << 4;
    *(float4*)(q8 + ((size_t)bh << 16) + (((size_t)(i0 + rr)) << 6) + p4) =
        *(const float4*)&Qs[rr][p4];
    if ((t & 3) == 0) Sq8[(bh << 10) + i0 + rr] = Sq[rr];
  }
  const v4i Bq = *(const v4i*)&Qs[(w << 4) + lr][lg << 4];
  const int sqi = Sq[(w << 4) + lr];

  int gmin = 0x7fffffff, gmax = (int)0x80000000, rmax = (int)0x80000000;
  for (int cc = 0; cc < 16; ++cc){
    __syncthreads();
    stage_tile(kg + ((size_t)(b*W + (cc << 6)) * NH + h) * DH, Ks, Sk, isk, kp.z, qmn, qmx, t);
    __syncthreads();
    if (CACHED && cc == it){
      const int rr = t >> 2, p4 = (t & 3) << 4;
      *(float4*)(k8 + ((size_t)bh << 16) + (((size_t)((cc << 6) + rr)) << 6) + p4) =
          *(const float4*)&Ks[rr][p4];
      if ((t & 3) == 0) Sk8[(bh << 10) + (cc << 6) + rr] = Sk[rr];
    }
    #pragma unroll
    for (int jt = 0; jt < 4; ++jt){
      v4i Ak = *(const v4i*)&Ks[(jt << 4) + lr][lg << 4];
      v4i zz = {0, 0, 0, 0};
      v4i acc = __builtin_amdgcn_mfma_i32_16x16x64_i8(Ak, Bq, zz, 0, 0, 0);
      v4i s4 = *(const v4i*)&Sk[(jt << 4) + (lg << 2)];
      #pragma unroll
      for (int r = 0; r < 4; ++r){
        int J = acc[r] - izq * s4[r] - izk * sqi + c64;
        gmin = min(gmin, J); gmax = max(gmax, J); rmax = max(rmax, J);
      }
    }
  }
  rmax = max(rmax, __shfl_xor(rmax, 16));
  rmax = max(rmax, __shfl_xor(rmax, 32));
  if (lg == 0)
    stash[((size_t)(b*W + i0 + (w << 4) + lr) * NH + h) * DH] = __int_as_float(rmax);
  const int idx = (it + bh * 16) & (NS - 1);
  blk_iminmax_atomic(gmin, gmax, jmn + idx, jmx + idx);
}

// pass2: per-row Z via in-register exp2 (-> stash d=1); global att max (=max 1/Z) -> slot 4.
template<bool CACHED>
__global__ __launch_bounds__(256) void pass2_kernel(const float* __restrict__ qg,
                                                    const float* __restrict__ kg,
                                                    unsigned* __restrict__ slots,
                                                    const int* __restrict__ jmn,
                                                    const int* __restrict__ jmx,
                                                    const int* __restrict__ bits_p,
                                                    float* __restrict__ stash,
                                                    const char* __restrict__ q8,
                                                    const char* __restrict__ k8,
                                                    const int* __restrict__ Sq8,
                                                    const int* __restrict__ Sk8){
  __shared__ __align__(16) signed char Qs[64][80], Ks[64][80];
  __shared__ int Sq[64], Sk[64];
  const int bits = *bits_p;
  const float qmx = (float)((1 << (bits-1)) - 1), qmn = -(float)(1 << (bits-1));
  const QP qq = qp_generic(slots, 0, qmn, qmx);
  const QP kp = qp_generic(slots, 1, qmn, qmx);
  const QP sp = qp_scores(jmn, jmx, qq.s, kp.s, qmn, qmx);
  const int it = blockIdx.x, bh = blockIdx.y, b = bh >> 3, h = bh & 7;
  const int i0 = it << 6, t = threadIdx.x;
  const int lane = t & 63, w = t >> 6, lr = lane & 15, lg = lane >> 4;
  const float isq = 1.0f / qq.s, isk = 1.0f / kp.s;
  const int izq = (int)qq.z, izk = (int)kp.z, c64 = 64 * izq * izk;
  const float rf = (0.125f * (qq.s * kp.s)) / sp.s;
  const float c2 = sp.s * L2E;
  const float zs = sp.z;
  const int irow = (w << 4) + lr;

  v4i Bq; int sqi;
  if (CACHED){
    Bq = *(const v4i*)(q8 + ((size_t)bh << 16) + (((size_t)(i0 + irow)) << 6) + (lg << 4));
    sqi = Sq8[(bh << 10) + i0 + irow];
  } else {
    stage_tile(qg + ((size_t)(b*W + i0) * NH + h) * DH, Qs, Sq, isq, qq.z, qmn, qmx, t);
    __syncthreads();
    Bq = *(const v4i*)&Qs[irow][lg << 4];
    sqi = Sq[irow];
  }
  int Jm = __float_as_int(stash[((size_t)(b*W + i0 + irow) * NH + h) * DH]);
  const float tmxf = fminf(fmaxf(rintf((float)Jm * rf) + zs, qmn), qmx);

  float zacc = 0.f;
  for (int cc = 0; cc < 16; ++cc){
    __syncthreads();
    if (CACHED)
      copy_tile(k8 + ((size_t)bh << 16) + ((size_t)(cc << 6) << 6), Sk8 + (bh << 10) + (cc << 6),
                Ks, Sk, t);
    else
      stage_tile(kg + ((size_t)(b*W + (cc << 6)) * NH + h) * DH, Ks, Sk, isk, kp.z, qmn, qmx, t);
    __syncthreads();
    #pragma unroll
    for (int jt = 0; jt < 4; ++jt){
      v4i Ak = *(const v4i*)&Ks[(jt << 4) + lr][lg << 4];
      v4i zz = {0, 0, 0, 0};
      v4i acc = __builtin_amdgcn_mfma_i32_16x16x64_i8(Ak, Bq, zz, 0, 0, 0);
      v4i s4 = *(const v4i*)&Sk[(jt << 4) + (lg << 2)];
      int J0 = acc[0] - izq * s4[0] - izk * sqi + c64;
      int J1 = acc[1] - izq * s4[1] - izk * sqi + c64;
      int J2 = acc[2] - izq * s4[2] - izk * sqi + c64;
      int J3 = acc[3] - izq * s4[3] - izk * sqi + c64;
      float tl0 = fminf(fmaxf(rintf((float)J0 * rf) + zs, qmn), qmx);
      float tl1 = fminf(fmaxf(rintf((float)J1 * rf) + zs, qmn), qmx);
      float tl2 = fminf(fmaxf(rintf((float)J2 * rf) + zs, qmn), qmx);
      float tl3 = fminf(fmaxf(rintf((float)J3 * rf) + zs, qmn), qmx);
      zacc += exp2f((tl0 - tmxf) * c2);
      zacc += exp2f((tl1 - tmxf) * c2);
      zacc += exp2f((tl2 - tmxf) * c2);
      zacc += exp2f((tl3 - tmxf) * c2);
    }
  }
  zacc += __shfl_xor(zacc, 16);
  zacc += __shfl_xor(zacc, 32);
  if (lg == 0)
    stash[((size_t)(b*W + i0 + irow) * NH + h) * DH + 1] = zacc;
  float ratt = 1.0f / zacc;            // row max of softmax = exp2(0)/Z = 1/Z exactly
  #pragma unroll
  for (int o = 1; o < 16; o <<= 1) ratt = fmaxf(ratt, __shfl_xor(ratt, o));
  if (lane == 0){
    const int idx = ((it << 2) + w + bh * 64) & (NS - 1);
    atomicMax(slot_max(slots, 4) + idx, enc_f(ratt));
  }
}

// pass3: recompute J, transform -> att_q (float4 out) + int8 PV-MFMA -> raw ctx + minmax.
template<bool CACHED>
__global__ __launch_bounds__(256) void pass3_kernel(const float* __restrict__ qg,
                                                    const float* __restrict__ kg,
                                                    const float* __restrict__ vg,
                                                    float* __restrict__ att,
                                                    float* __restrict__ ctx,
                                                    unsigned* __restrict__ slots,
                                                    const int* __restrict__ jmn,
                                                    const int* __restrict__ jmx,
                                                    const int* __restrict__ bits_p,
                                                    const char* __restrict__ q8,
                                                    const char* __restrict__ k8,
                                                    const int* __restrict__ Sq8,
                                                    const int* __restrict__ Sk8){
  __shared__ __align__(16) signed char Qs[64][80], Ks[64][80], Vs[64][80], As[64][80];
  __shared__ int Sq[64], Sk[64];
  __shared__ int RowA[64], ColV[64];
  const int bits = *bits_p;
  const float qmx = (float)((1 << (bits-1)) - 1), qmn = -(float)(1 << (bits-1));
  const QP qq = qp_generic(slots, 0, qmn, qmx);
  const QP kp = qp_generic(slots, 1, qmn, qmx);
  const QP sp = qp_scores(jmn, jmx, qq.s, kp.s, qmn, qmx);
  const QP vp = qp_generic(slots, 2, qmn, qmx);
  const QP ap = qp_generic(slots, 4, qmn, qmx);
  const int it = blockIdx.x, bh = blockIdx.y, b = bh >> 3, h = bh & 7;
  const int i0 = it << 6, t = threadIdx.x;
  const int lane = t & 63, w = t >> 6, lr = lane & 15, lg = lane >> 4;
  const float isq = 1.0f / qq.s, isk = 1.0f / kp.s;
  const int izq = (int)qq.z, izk = (int)kp.z, c64 = 64 * izq * izk;
  const float rf = (0.125f * (qq.s * kp.s)) / sp.s;
  const float c2 = sp.s * L2E, zs = sp.z;
  const float sa = ap.s, za = ap.z, inv_sa = 1.0f / sa;
  const float sv = vp.s, zv = vp.z, isv = 1.0f / sv;
  const int iza = (int)za, izv = (int)zv;
  const int irow = (w << 4) + lr;

  if (t < 64) ColV[t] = 0;
  v4i Bq; int sqi;
  if (CACHED){
    Bq = *(const v4i*)(q8 + ((size_t)bh << 16) + (((size_t)(i0 + irow)) << 6) + (lg << 4));
    sqi = Sq8[(bh << 10) + i0 + irow];
  } else {
    stage_tile(qg + ((size_t)(b*W + i0) * NH + h) * DH, Qs, Sq, isq, qq.z, qmn, qmx, t);
    __syncthreads();
    Bq = *(const v4i*)&Qs[irow][lg << 4];
    sqi = Sq[irow];
  }
  const size_t rbase = ((size_t)(b*W + i0 + irow) * NH + h) * DH;
  int Jm = __float_as_int(ctx[rbase]);
  const float tmxf = fminf(fmaxf(rintf((float)Jm * rf) + zs, qmn), qmx);
  const float iZ = 1.0f / ctx[rbase + 1];

  const int dq4 = (t & 15) << 2;       // V: 4 d's per thread
  const int kb  = (t >> 4) << 2;       // V: 4 kk's per thread
  int cv4[4] = {0, 0, 0, 0};
  int rA = 0;
  v4i accPV[4];
  #pragma unroll
  for (int tj = 0; tj < 4; ++tj){ v4i zz = {0,0,0,0}; accPV[tj] = zz; }

  for (int cc = 0; cc < 16; ++cc){
    __syncthreads();
    if (CACHED)
      copy_tile(k8 + ((size_t)bh << 16) + ((size_t)(cc << 6) << 6), Sk8 + (bh << 10) + (cc << 6),
                Ks, Sk, t);
    else
      stage_tile(kg + ((size_t)(b*W + (cc << 6)) * NH + h) * DH, Ks, Sk, isk, kp.z, qmn, qmx, t);
    {
      const float* vp_ = vg + ((size_t)(b*W + (cc << 6) + kb) * NH + h) * DH + dq4;
      float4 x0 = *(const float4*)(vp_);
      float4 x1 = *(const float4*)(vp_ + ROWF);
      float4 x2 = *(const float4*)(vp_ + 2 * ROWF);
      float4 x3 = *(const float4*)(vp_ + 3 * ROWF);
      int q00 = qint_m(x0.x, isv, zv, qmn, qmx), q01 = qint_m(x0.y, isv, zv, qmn, qmx),
          q02 = qint_m(x0.z, isv, zv, qmn, qmx), q03 = qint_m(x0.w, isv, zv, qmn, qmx);
      int q10 = qint_m(x1.x, isv, zv, qmn, qmx), q11 = qint_m(x1.y, isv, zv, qmn, qmx),
          q12 = qint_m(x1.z, isv, zv, qmn, qmx), q13 = qint_m(x1.w, isv, zv, qmn, qmx);
      int q20 = qint_m(x2.x, isv, zv, qmn, qmx), q21 = qint_m(x2.y, isv, zv, qmn, qmx),
          q22 = qint_m(x2.z, isv, zv, qmn, qmx), q23 = qint_m(x2.w, isv, zv, qmn, qmx);
      int q30 = qint_m(x3.x, isv, zv, qmn, qmx), q31 = qint_m(x3.y, isv, zv, qmn, qmx),
          q32 = qint_m(x3.z, isv, zv, qmn, qmx), q33 = qint_m(x3.w, isv, zv, qmn, qmx);
      cv4[0] += q00 + q10 + q20 + q30;
      cv4[1] += q01 + q11 + q21 + q31;
      cv4[2] += q02 + q12 + q22 + q32;
      cv4[3] += q03 + q13 + q23 + q33;
      *(unsigned*)&Vs[dq4 + 0][kb] = pack4(q00, q10, q20, q30);
      *(unsigned*)&Vs[dq4 + 1][kb] = pack4(q01, q11, q21, q31);
      *(unsigned*)&Vs[dq4 + 2][kb] = pack4(q02, q12, q22, q32);
      *(unsigned*)&Vs[dq4 + 3][kb] = pack4(q03, q13, q23, q33);
    }
    __syncthreads();
    #pragma unroll
    for (int jt = 0; jt < 4; ++jt){
      v4i Ak = *(const v4i*)&Ks[(jt << 4) + lr][lg << 4];
      v4i zz = {0, 0, 0, 0};
      v4i acc = __builtin_amdgcn_mfma_i32_16x16x64_i8(Ak, Bq, zz, 0, 0, 0);
      v4i s4 = *(const v4i*)&Sk[(jt << 4) + (lg << 2)];
      int J0 = acc[0] - izq * s4[0] - izk * sqi + c64;
      int J1 = acc[1] - izq * s4[1] - izk * sqi + c64;
      int J2 = acc[2] - izq * s4[2] - izk * sqi + c64;
      int J3 = acc[3] - izq * s4[3] - izk * sqi + c64;
      float tl0 = fminf(fmaxf(rintf((float)J0 * rf) + zs, qmn), qmx);
      float tl1 = fminf(fmaxf(rintf((float)J1 * rf) + zs, qmn), qmx);
      float tl2 = fminf(fmaxf(rintf((float)J2 * rf) + zs, qmn), qmx);
      float tl3 = fminf(fmaxf(rintf((float)J3 * rf) + zs, qmn), qmx);
      float p0 = exp2f((tl0 - tmxf) * c2) * iZ;
      float p1 = exp2f((tl1 - tmxf) * c2) * iZ;
      float p2 = exp2f((tl2 - tmxf) * c2) * iZ;
      float p3 = exp2f((tl3 - tmxf) * c2) * iZ;
      float a0 = fminf(fmaxf(rintf(p0 * inv_sa) + za, qmn), qmx);
      float a1 = fminf(fmaxf(rintf(p1 * inv_sa) + za, qmn), qmx);
      float a2 = fminf(fmaxf(rintf(p2 * inv_sa) + za, qmn), qmx);
      float a3 = fminf(fmaxf(rintf(p3 * inv_sa) + za, qmn), qmx);
      float4 y;
      y.x = (a0 - za) * sa; y.y = (a1 - za) * sa;
      y.z = (a2 - za) * sa; y.w = (a3 - za) * sa;
      *(float4*)(att + ((size_t)bh << 20) + (size_t)(i0 + irow) * W
                 + (cc << 6) + (jt << 4) + (lg << 2)) = y;
      int q0 = (int)a0, q1 = (int)a1, q2 = (int)a2, q3 = (int)a3;
      rA += q0 + q1 + q2 + q3;
      *(unsigned*)&As[irow][(jt << 4) + (lg << 2)] = pack4(q0, q1, q2, q3);
    }
    // As rows of this wave written only by this wave; LDS ops in-order -> no barrier
    {
      v4i A2 = *(const v4i*)&As[(w << 4) + lr][lg << 4];
      #pragma unroll
      for (int tj = 0; tj < 4; ++tj){
        v4i B2 = *(const v4i*)&Vs[(tj << 4) + lr][lg << 4];
        accPV[tj] = __builtin_amdgcn_mfma_i32_16x16x64_i8(A2, B2, accPV[tj], 0, 0, 0);
      }
    }
  }

  rA += __shfl_xor(rA, 16);
  rA += __shfl_xor(rA, 32);
  if (lg == 0) RowA[irow] = rA;
  #pragma unroll
  for (int j = 0; j < 4; ++j) atomicAdd(&ColV[dq4 + j], cv4[j]);
  __syncthreads();

  const float sav = sa * sv;
  float lmin = 0.f, lmax = 0.f;
  #pragma unroll
  for (int tj = 0; tj < 4; ++tj){
    const int d = (tj << 4) + lr;
    #pragma unroll
    for (int r = 0; r < 4; ++r){
      const int i = (w << 4) + (lg << 2) + r;
      int Jv = accPV[tj][r] - iza * ColV[d] - izv * RowA[i] + 1024 * iza * izv;
      float c = sav * (float)Jv;
      lmin = fminf(lmin, c); lmax = fmaxf(lmax, c);
      ctx[(((size_t)(b * W + i0 + i)) * NH + h) * DH + d] = c;
    }
  }
  const int idx = (it + bh * 16) & (NS - 1);
  blk_minmax_atomic(lmin, lmax, slot_min(slots, 5) + idx, slot_max(slots, 5) + idx);
}

__global__ __launch_bounds__(256) void quantctx_kernel(float* __restrict__ ctx,
                                                       const unsigned* __restrict__ slots,
                                                       const int* __restrict__ bits_p){
  const int bits = *bits_p;
  const float qmx = (float)((1 << (bits-1)) - 1), qmn = -(float)(1 << (bits-1));
  const QP cp = qp_generic(slots, 5, qmn, qmx);
  size_t i = (size_t)blockIdx.x * blockDim.x + threadIdx.x;   // float4 index
  float4* p = (float4*)ctx;
  float4 x = p[i];
  x.x = fq1(x.x, cp.s, cp.z, qmn, qmx);
  x.y = fq1(x.y, cp.s, cp.z, qmn, qmx);
  x.z = fq1(x.z, cp.s, cp.z, qmn, qmx);
  x.w = fq1(x.w, cp.s, cp.z, qmn, qmx);
  p[i] = x;
}

// ---------- launch ----------

extern "C" void kernel_launch(void* const* d_in, const int* in_sizes, int n_in,
                              void* d_out, int out_size, void* d_ws, size_t ws_size,
                              hipStream_t stream){
  const float* q = (const float*)d_in[0];
  const float* k = (const float*)d_in[1];
  const float* v = (const float*)d_in[2];
  const int* bits = (const int*)d_in[3];
  float* ctx = (float*)d_out;                      // hosts per-row {Jmax,Z} stash (d=0,1)
  float* att = (float*)d_out + CTX_ELEMS;          // att_q output (written once, in pass3)
  unsigned* slots = (unsigned*)d_ws;               // 768 uints (3072 B)
  int* jmn = (int*)((char*)d_ws + 3072);           // 64 ints
  int* jmx = (int*)((char*)d_ws + 3328);           // 64 ints
  // int8 Q/K cache blobs (pass1 -> pass2/pass3); total end = 8,916,992 B
  int* Sq8 = (int*)((char*)d_ws + 4096);           // 256 KB
  int* Sk8 = (int*)((char*)d_ws + 266240);         // 256 KB
  char* q8 = (char*)d_ws + 528384;                 // 4 MB
  char* k8 = (char*)d_ws + 4722688;                // 4 MB
  const bool cached = ws_size >= (size_t)9000000;

  hipLaunchKernelGGL(init_slots_kernel, dim3(1), dim3(256), 0, stream, slots, jmn, jmx);
  hipLaunchKernelGGL(minmax3_kernel, dim3(512, 3), dim3(256), 0, stream, q, k, v, slots);
  if (cached){
    hipLaunchKernelGGL(pass1_kernel<true>, dim3(16, BHN), dim3(256), 0, stream,
                       q, k, slots, bits, ctx, jmn, jmx, q8, k8, Sq8, Sk8);
    hipLaunchKernelGGL(pass2_kernel<true>, dim3(16, BHN), dim3(256), 0, stream,
                       q, k, slots, jmn, jmx, bits, ctx, q8, k8, Sq8, Sk8);
    hipLaunchKernelGGL(pass3_kernel<true>, dim3(16, BHN), dim3(256), 0, stream,
                       q, k, v, att, ctx, slots, jmn, jmx, bits, q8, k8, Sq8, Sk8);
  } else {
    hipLaunchKernelGGL(pass1_kernel<false>, dim3(16, BHN), dim3(256), 0, stream,
                       q, k, slots, bits, ctx, jmn, jmx, q8, k8, Sq8, Sk8);
    hipLaunchKernelGGL(pass2_kernel<false>, dim3(16, BHN), dim3(256), 0, stream,
                       q, k, slots, jmn, jmx, bits, ctx, q8, k8, Sq8, Sk8);
    hipLaunchKernelGGL(pass3_kernel<false>, dim3(16, BHN), dim3(256), 0, stream,
                       q, k, v, att, ctx, slots, jmn, jmx, bits, q8, k8, Sq8, Sk8);
  }
  hipLaunchKernelGGL(quantctx_kernel, dim3(4096), dim3(256), 0, stream, ctx, slots, bits);
}

// Round 9
// 210.477 us; speedup vs baseline: 1.3371x; 1.0668x over previous
//
#include <hip/hip_runtime.h>
#include <cstdint>
#include <cstddef>

// Problem shape (fixed by setup_inputs): B=8, W=1024, H=8, D=64
#define W  1024
#define NH 8
#define NB 8
#define DH 64
#define BHN (NB*NH)                      // 64 batch-heads
#define CTX_ELEMS ((size_t)NB*W*NH*DH)   // 4194304
#define NS 64                            // atomic spread width
#define ROWF 512                         // row stride in floats (NH*DH)
#define L2E 1.4426950408889634f

typedef int v4i __attribute__((ext_vector_type(4)));

// ---------- helpers ----------

__device__ __forceinline__ unsigned enc_f(float f){
  unsigned u = __float_as_uint(f);
  return (u & 0x80000000u) ? ~u : (u | 0x80000000u);
}
__device__ __forceinline__ float dec_f(unsigned k){
  unsigned u = (k & 0x80000000u) ? (k ^ 0x80000000u) : ~k;
  return __uint_as_float(u);
}

__device__ __forceinline__ float fq1(float x, float s, float z, float mn, float mx){
  float t = rintf(x / s) + z;
  t = fminf(fmaxf(t, mn), mx);
  return (t - z) * s;
}
__device__ __forceinline__ int qint_m(float x, float is, float z, float mn, float mx){
  return (int)fminf(fmaxf(rintf(x * is) + z, mn), mx);
}
__device__ __forceinline__ unsigned pack4(int a0, int a1, int a2, int a3){
  return (unsigned)(a0 & 0xff) | ((unsigned)(a1 & 0xff) << 8) |
         ((unsigned)(a2 & 0xff) << 16) | ((unsigned)(a3 & 0xff) << 24);
}

__device__ __forceinline__ unsigned* slot_min(unsigned* s, int t){ return s + (size_t)(2*t)*NS; }
__device__ __forceinline__ unsigned* slot_max(unsigned* s, int t){ return s + (size_t)(2*t+1)*NS; }

struct QP { float s, z; };

__device__ __forceinline__ QP qp_generic(const unsigned* slots, int t, float qmn, float qmx){
  const unsigned* pm = slots + (size_t)(2*t)*NS;
  const unsigned* px = pm + NS;
  unsigned em = pm[0], ex = px[0];
  for (int i = 1; i < NS; ++i){
    unsigned a = pm[i], b = px[i];
    em = (a < em) ? a : em;
    ex = (b > ex) ? b : ex;
  }
  float mn = dec_f(em), mx = dec_f(ex);
  QP r;
  r.s = fmaxf((mx - mn) / (qmx - qmn), 1e-8f);
  r.z = fminf(fmaxf(rintf(qmn - mn / r.s), qmn), qmx);
  return r;
}
__device__ __forceinline__ QP qp_scores(const int* jmn, const int* jmx, float sq, float sk,
                                        float qmn, float qmx){
  int em = jmn[0], ex = jmx[0];
  for (int i = 1; i < NS; ++i){ em = min(em, jmn[i]); ex = max(ex, jmx[i]); }
  float cfac = 0.125f * (sq * sk);
  float mn = fminf(cfac * (float)em, 0.0f);
  float mx = fmaxf(cfac * (float)ex, 0.0f);
  QP r;
  r.s = fmaxf((mx - mn) / (qmx - qmn), 1e-8f);
  r.z = fminf(fmaxf(rintf(qmn - mn / r.s), qmn), qmx);
  return r;
}

__device__ __forceinline__ void blk_minmax_atomic(float lmin, float lmax,
                                                  unsigned* smin, unsigned* smax){
  #pragma unroll
  for (int o = 32; o; o >>= 1){
    lmin = fminf(lmin, __shfl_xor(lmin, o));
    lmax = fmaxf(lmax, __shfl_xor(lmax, o));
  }
  __shared__ float wmn[4], wmx[4];
  int wid = threadIdx.x >> 6, lane = threadIdx.x & 63;
  if (lane == 0){ wmn[wid] = lmin; wmx[wid] = lmax; }
  __syncthreads();
  if (threadIdx.x == 0){
    float a = wmn[0], b = wmx[0];
    for (int w = 1; w < (int)(blockDim.x >> 6); ++w){
      a = fminf(a, wmn[w]); b = fmaxf(b, wmx[w]);
    }
    atomicMin(smin, enc_f(a));
    atomicMax(smax, enc_f(b));
  }
}

__device__ __forceinline__ void blk_iminmax_atomic(int lmin, int lmax, int* gmin, int* gmax){
  #pragma unroll
  for (int o = 32; o; o >>= 1){
    lmin = min(lmin, __shfl_xor(lmin, o));
    lmax = max(lmax, __shfl_xor(lmax, o));
  }
  __shared__ int iwmn[4], iwmx[4];
  int wid = threadIdx.x >> 6, lane = threadIdx.x & 63;
  if (lane == 0){ iwmn[wid] = lmin; iwmx[wid] = lmax; }
  __syncthreads();
  if (threadIdx.x == 0){
    int a = iwmn[0], b = iwmx[0];
    for (int w = 1; w < (int)(blockDim.x >> 6); ++w){
      a = min(a, iwmn[w]); b = max(b, iwmx[w]);
    }
    atomicMin(gmin, a);
    atomicMax(gmax, b);
  }
}

// stage a 64x64 fp32 tile -> int8 LDS [row][d] (+row sums) — plain path only
__device__ __forceinline__ void stage_tile(const float* __restrict__ rowptr,
                                           signed char (*S)[80], int* __restrict__ Ssum,
                                           float is, float z, float mn, float mx, int t){
  const int rr = t >> 2, dq = (t & 3) << 4;
  const float* p = rowptr + (size_t)rr * ROWF + dq;
  int part = 0;
  #pragma unroll
  for (int g = 0; g < 4; ++g){
    float4 x = *(const float4*)(p + g * 4);
    int a0 = qint_m(x.x, is, z, mn, mx), a1 = qint_m(x.y, is, z, mn, mx);
    int a2 = qint_m(x.z, is, z, mn, mx), a3 = qint_m(x.w, is, z, mn, mx);
    part += a0 + a1 + a2 + a3;
    *(unsigned*)&S[rr][dq + g*4] = pack4(a0, a1, a2, a3);
  }
  int x1 = part + __shfl_xor(part, 1);
  int tot = x1 + __shfl_xor(x1, 2);
  if ((t & 3) == 0) Ssum[rr] = tot;
}

// quantize this lane's Q fragment (row, d = lg*16..+16) into regs + full 64-d row sum
__device__ __forceinline__ v4i qfrag_direct(const float* __restrict__ qrow, int lg,
                                            float is, float z, float mn, float mx,
                                            int* sqi_out){
  const float* p = qrow + (lg << 4);
  int part = 0; unsigned d4[4];
  #pragma unroll
  for (int g = 0; g < 4; ++g){
    float4 x = *(const float4*)(p + g * 4);
    int a0 = qint_m(x.x, is, z, mn, mx), a1 = qint_m(x.y, is, z, mn, mx);
    int a2 = qint_m(x.z, is, z, mn, mx), a3 = qint_m(x.w, is, z, mn, mx);
    part += a0 + a1 + a2 + a3;
    d4[g] = pack4(a0, a1, a2, a3);
  }
  part += __shfl_xor(part, 16);   // sum over lg partials (lanes differ in bits 4,5)
  part += __shfl_xor(part, 32);
  *sqi_out = part;
  v4i r; r[0] = (int)d4[0]; r[1] = (int)d4[1]; r[2] = (int)d4[2]; r[3] = (int)d4[3];
  return r;
}

// ---------- kernels ----------

__global__ void init_slots_kernel(unsigned* __restrict__ slots, int* __restrict__ jmn,
                                  int* __restrict__ jmx, int* __restrict__ Sv8){
  for (int i = threadIdx.x; i < 6*2*NS; i += blockDim.x)
    slots[i] = 0x80000000u;   // enc(0.0f): reference clamps min<=0<=max
  if (threadIdx.x < NS){
    jmn[threadIdx.x] = 0x7fffffff;
    jmx[threadIdx.x] = (int)0x80000000;
  }
  for (int i = threadIdx.x; i < BHN*64; i += blockDim.x) Sv8[i] = 0;
}

__global__ __launch_bounds__(256) void minmax3_kernel(const float* __restrict__ q,
                                                      const float* __restrict__ k,
                                                      const float* __restrict__ v,
                                                      unsigned* __restrict__ slots){
  const float4* p = (const float4*)(blockIdx.y == 0 ? q : (blockIdx.y == 1 ? k : v));
  float lmin = 0.f, lmax = 0.f;
  const int n4 = (int)(CTX_ELEMS / 4);
  for (int i = blockIdx.x * blockDim.x + threadIdx.x; i < n4; i += gridDim.x * blockDim.x){
    float4 x = p[i];
    lmin = fminf(lmin, fminf(fminf(x.x, x.y), fminf(x.z, x.w)));
    lmax = fmaxf(lmax, fmaxf(fmaxf(x.x, x.y), fmaxf(x.z, x.w)));
  }
  const int idx = blockIdx.x & (NS - 1);
  blk_minmax_atomic(lmin, lmax, slot_min(slots, blockIdx.y) + idx, slot_max(slots, blockIdx.y) + idx);
}

// ===== cached path =====

// pass1a: quantize K rows -> k8[bh][kk][d] + Sk8 row sums; V rows -> v8[bh][d][kk]
// (transposed, dword-packed over kk) + Sv8 column sums. 1x coverage, no MFMA.
__global__ __launch_bounds__(256) void pass1a_kernel(const float* __restrict__ kg,
                                                     const float* __restrict__ vg,
                                                     const unsigned* __restrict__ slots,
                                                     const int* __restrict__ bits_p,
                                                     char* __restrict__ k8,
                                                     int* __restrict__ Sk8,
                                                     char* __restrict__ v8,
                                                     int* __restrict__ Sv8){
  __shared__ int ColS[64];
  const int bits = *bits_p;
  const float qmx = (float)((1 << (bits-1)) - 1), qmn = -(float)(1 << (bits-1));
  const QP kp = qp_generic(slots, 1, qmn, qmx);
  const QP vp = qp_generic(slots, 2, qmn, qmx);
  const int it = blockIdx.x, bh = blockIdx.y, b = bh >> 3, h = bh & 7;
  const int i0 = it << 6, t = threadIdx.x;

  // K: thread rr = t>>2, dq = (t&3)*16
  {
    const int rr = t >> 2, dq = (t & 3) << 4;
    const float* p = kg + ((size_t)(b*W + i0 + rr) * NH + h) * DH + dq;
    const float isk = 1.0f / kp.s;
    int part = 0; unsigned d4[4];
    #pragma unroll
    for (int g = 0; g < 4; ++g){
      float4 x = *(const float4*)(p + g * 4);
      int a0 = qint_m(x.x, isk, kp.z, qmn, qmx), a1 = qint_m(x.y, isk, kp.z, qmn, qmx);
      int a2 = qint_m(x.z, isk, kp.z, qmn, qmx), a3 = qint_m(x.w, isk, kp.z, qmn, qmx);
      part += a0 + a1 + a2 + a3;
      d4[g] = pack4(a0, a1, a2, a3);
    }
    uint4 u; u.x = d4[0]; u.y = d4[1]; u.z = d4[2]; u.w = d4[3];
    *(uint4*)(k8 + ((size_t)bh << 16) + (((size_t)(i0 + rr)) << 6) + dq) = u;
    int x1 = part + __shfl_xor(part, 1);
    int tot = x1 + __shfl_xor(x1, 2);
    if ((t & 3) == 0) Sk8[(bh << 10) + i0 + rr] = tot;
  }

  // V: thread dq4 = (t&15)*4 (4 d's), kb = (t>>4)*4 (4 kk's in [i0,i0+64))
  {
    const int dq4 = (t & 15) << 2, kb = (t >> 4) << 2;
    const float* vp_ = vg + ((size_t)(b*W + i0 + kb) * NH + h) * DH + dq4;
    const float isv = 1.0f / vp.s;
    float4 x0 = *(const float4*)(vp_);
    float4 x1 = *(const float4*)(vp_ + ROWF);
    float4 x2 = *(const float4*)(vp_ + 2 * ROWF);
    float4 x3 = *(const float4*)(vp_ + 3 * ROWF);
    int q00 = qint_m(x0.x, isv, vp.z, qmn, qmx), q01 = qint_m(x0.y, isv, vp.z, qmn, qmx),
        q02 = qint_m(x0.z, isv, vp.z, qmn, qmx), q03 = qint_m(x0.w, isv, vp.z, qmn, qmx);
    int q10 = qint_m(x1.x, isv, vp.z, qmn, qmx), q11 = qint_m(x1.y, isv, vp.z, qmn, qmx),
        q12 = qint_m(x1.z, isv, vp.z, qmn, qmx), q13 = qint_m(x1.w, isv, vp.z, qmn, qmx);
    int q20 = qint_m(x2.x, isv, vp.z, qmn, qmx), q21 = qint_m(x2.y, isv, vp.z, qmn, qmx),
        q22 = qint_m(x2.z, isv, vp.z, qmn, qmx), q23 = qint_m(x2.w, isv, vp.z, qmn, qmx);
    int q30 = qint_m(x3.x, isv, vp.z, qmn, qmx), q31 = qint_m(x3.y, isv, vp.z, qmn, qmx),
        q32 = qint_m(x3.z, isv, vp.z, qmn, qmx), q33 = qint_m(x3.w, isv, vp.z, qmn, qmx);
    unsigned w0 = pack4(q00, q10, q20, q30);
    unsigned w1 = pack4(q01, q11, q21, q31);
    unsigned w2 = pack4(q02, q12, q22, q32);
    unsigned w3 = pack4(q03, q13, q23, q33);
    char* vb = v8 + ((size_t)bh << 16) + i0 + kb;
    *(unsigned*)(vb + ((size_t)(dq4 + 0) << 10)) = w0;
    *(unsigned*)(vb + ((size_t)(dq4 + 1) << 10)) = w1;
    *(unsigned*)(vb + ((size_t)(dq4 + 2) << 10)) = w2;
    *(unsigned*)(vb + ((size_t)(dq4 + 3) << 10)) = w3;
    int cv0 = q00 + q10 + q20 + q30;
    int cv1 = q01 + q11 + q21 + q31;
    int cv2 = q02 + q12 + q22 + q32;
    int cv3 = q03 + q13 + q23 + q33;
    if (t < 64) ColS[t] = 0;
    __syncthreads();
    atomicAdd(&ColS[dq4 + 0], cv0);
    atomicAdd(&ColS[dq4 + 1], cv1);
    atomicAdd(&ColS[dq4 + 2], cv2);
    atomicAdd(&ColS[dq4 + 3], cv3);
    __syncthreads();
    if (t < 64) atomicAdd(&Sv8[(bh << 6) + t], ColS[t]);
  }
}

// pass1b: barrier-free QK J min/max + per-row Jmax -> ctx stash d=0.
__global__ __launch_bounds__(256) void pass1b_kernel(const float* __restrict__ qg,
                                                     const unsigned* __restrict__ slots,
                                                     const int* __restrict__ bits_p,
                                                     float* __restrict__ stash,
                                                     int* __restrict__ jmn,
                                                     int* __restrict__ jmx,
                                                     const char* __restrict__ k8,
                                                     const int* __restrict__ Sk8){
  const int bits = *bits_p;
  const float qmx = (float)((1 << (bits-1)) - 1), qmn = -(float)(1 << (bits-1));
  const QP qq = qp_generic(slots, 0, qmn, qmx);
  const QP kp = qp_generic(slots, 1, qmn, qmx);
  const int it = blockIdx.x, bh = blockIdx.y, b = bh >> 3, h = bh & 7;
  const int i0 = it << 6, t = threadIdx.x;
  const int lane = t & 63, w = t >> 6, lr = lane & 15, lg = lane >> 4;
  const int irow = (w << 4) + lr;
  const int izq = (int)qq.z, izk = (int)kp.z, c64 = 64 * izq * izk;

  int sqi;
  v4i Bq = qfrag_direct(qg + ((size_t)(b*W + i0 + irow) * NH + h) * DH, lg,
                        1.0f / qq.s, qq.z, qmn, qmx, &sqi);
  const char* kb = k8 + ((size_t)bh << 16);
  const int* skb = Sk8 + (bh << 10);

  int gmin = 0x7fffffff, gmax = (int)0x80000000, rmax = (int)0x80000000;
  for (int cc = 0; cc < 16; ++cc){
    #pragma unroll
    for (int jt = 0; jt < 4; ++jt){
      v4i Ak = *(const v4i*)(kb + (((size_t)((cc << 6) + (jt << 4) + lr)) << 6) + (lg << 4));
      v4i s4 = *(const v4i*)(skb + (cc << 6) + (jt << 4) + (lg << 2));
      v4i zz = {0, 0, 0, 0};
      v4i acc = __builtin_amdgcn_mfma_i32_16x16x64_i8(Ak, Bq, zz, 0, 0, 0);
      #pragma unroll
      for (int r = 0; r < 4; ++r){
        int J = acc[r] - izq * s4[r] - izk * sqi + c64;
        gmin = min(gmin, J); gmax = max(gmax, J); rmax = max(rmax, J);
      }
    }
  }
  rmax = max(rmax, __shfl_xor(rmax, 16));
  rmax = max(rmax, __shfl_xor(rmax, 32));
  if (lg == 0)
    stash[((size_t)(b*W + i0 + irow) * NH + h) * DH] = __int_as_float(rmax);
  const int idx = (it + bh * 16) & (NS - 1);
  blk_iminmax_atomic(gmin, gmax, jmn + idx, jmx + idx);
}

// pass2c: barrier-free per-row Z -> stash d=1; global att max -> slot 4.
__global__ __launch_bounds__(256) void pass2c_kernel(const float* __restrict__ qg,
                                                     unsigned* __restrict__ slots,
                                                     const int* __restrict__ jmn,
                                                     const int* __restrict__ jmx,
                                                     const int* __restrict__ bits_p,
                                                     float* __restrict__ stash,
                                                     const char* __restrict__ k8,
                                                     const int* __restrict__ Sk8){
  const int bits = *bits_p;
  const float qmx = (float)((1 << (bits-1)) - 1), qmn = -(float)(1 << (bits-1));
  const QP qq = qp_generic(slots, 0, qmn, qmx);
  const QP kp = qp_generic(slots, 1, qmn, qmx);
  const QP sp = qp_scores(jmn, jmx, qq.s, kp.s, qmn, qmx);
  const int it = blockIdx.x, bh = blockIdx.y, b = bh >> 3, h = bh & 7;
  const int i0 = it << 6, t = threadIdx.x;
  const int lane = t & 63, w = t >> 6, lr = lane & 15, lg = lane >> 4;
  const int irow = (w << 4) + lr;
  const int izq = (int)qq.z, izk = (int)kp.z, c64 = 64 * izq * izk;
  const float rf = (0.125f * (qq.s * kp.s)) / sp.s;
  const float c2 = sp.s * L2E, zs = sp.z;

  int sqi;
  v4i Bq = qfrag_direct(qg + ((size_t)(b*W + i0 + irow) * NH + h) * DH, lg,
                        1.0f / qq.s, qq.z, qmn, qmx, &sqi);
  int Jm = __float_as_int(stash[((size_t)(b*W + i0 + irow) * NH + h) * DH]);
  const float tmxf = fminf(fmaxf(rintf((float)Jm * rf) + zs, qmn), qmx);
  const char* kb = k8 + ((size_t)bh << 16);
  const int* skb = Sk8 + (bh << 10);

  float zacc = 0.f;
  for (int cc = 0; cc < 16; ++cc){
    #pragma unroll
    for (int jt = 0; jt < 4; ++jt){
      v4i Ak = *(const v4i*)(kb + (((size_t)((cc << 6) + (jt << 4) + lr)) << 6) + (lg << 4));
      v4i s4 = *(const v4i*)(skb + (cc << 6) + (jt << 4) + (lg << 2));
      v4i zz = {0, 0, 0, 0};
      v4i acc = __builtin_amdgcn_mfma_i32_16x16x64_i8(Ak, Bq, zz, 0, 0, 0);
      int J0 = acc[0] - izq * s4[0] - izk * sqi + c64;
      int J1 = acc[1] - izq * s4[1] - izk * sqi + c64;
      int J2 = acc[2] - izq * s4[2] - izk * sqi + c64;
      int J3 = acc[3] - izq * s4[3] - izk * sqi + c64;
      float tl0 = fminf(fmaxf(rintf((float)J0 * rf) + zs, qmn), qmx);
      float tl1 = fminf(fmaxf(rintf((float)J1 * rf) + zs, qmn), qmx);
      float tl2 = fminf(fmaxf(rintf((float)J2 * rf) + zs, qmn), qmx);
      float tl3 = fminf(fmaxf(rintf((float)J3 * rf) + zs, qmn), qmx);
      zacc += exp2f((tl0 - tmxf) * c2);
      zacc += exp2f((tl1 - tmxf) * c2);
      zacc += exp2f((tl2 - tmxf) * c2);
      zacc += exp2f((tl3 - tmxf) * c2);
    }
  }
  zacc += __shfl_xor(zacc, 16);
  zacc += __shfl_xor(zacc, 32);
  if (lg == 0)
    stash[((size_t)(b*W + i0 + irow) * NH + h) * DH + 1] = zacc;
  float ratt = 1.0f / zacc;            // row max of softmax = exp2(0)/Z = 1/Z exactly
  #pragma unroll
  for (int o = 1; o < 16; o <<= 1) ratt = fmaxf(ratt, __shfl_xor(ratt, o));
  if (lane == 0){
    const int idx = ((it << 2) + w + bh * 64) & (NS - 1);
    atomicMax(slot_max(slots, 4) + idx, enc_f(ratt));
  }
}

// pass3c: barrier-free transform -> att_q + int8 PV-MFMA (V from v8 blob) -> raw ctx.
__global__ __launch_bounds__(256) void pass3c_kernel(const float* __restrict__ qg,
                                                     float* __restrict__ att,
                                                     float* __restrict__ ctx,
                                                     unsigned* __restrict__ slots,
                                                     const int* __restrict__ jmn,
                                                     const int* __restrict__ jmx,
                                                     const int* __restrict__ bits_p,
                                                     const char* __restrict__ k8,
                                                     const int* __restrict__ Sk8,
                                                     const char* __restrict__ v8,
                                                     const int* __restrict__ Sv8){
  __shared__ __align__(16) signed char As[64][80];
  __shared__ int RowA[64];
  const int bits = *bits_p;
  const float qmx = (float)((1 << (bits-1)) - 1), qmn = -(float)(1 << (bits-1));
  const QP qq = qp_generic(slots, 0, qmn, qmx);
  const QP kp = qp_generic(slots, 1, qmn, qmx);
  const QP sp = qp_scores(jmn, jmx, qq.s, kp.s, qmn, qmx);
  const QP vp = qp_generic(slots, 2, qmn, qmx);
  const QP ap = qp_generic(slots, 4, qmn, qmx);
  const int it = blockIdx.x, bh = blockIdx.y, b = bh >> 3, h = bh & 7;
  const int i0 = it << 6, t = threadIdx.x;
  const int lane = t & 63, w = t >> 6, lr = lane & 15, lg = lane >> 4;
  const int irow = (w << 4) + lr;
  const int izq = (int)qq.z, izk = (int)kp.z, c64 = 64 * izq * izk;
  const int iza = (int)ap.z, izv = (int)vp.z;
  const float rf = (0.125f * (qq.s * kp.s)) / sp.s;
  const float c2 = sp.s * L2E, zs = sp.z;
  const float sa = ap.s, za = ap.z, inv_sa = 1.0f / sa;

  int sqi;
  v4i Bq = qfrag_direct(qg + ((size_t)(b*W + i0 + irow) * NH + h) * DH, lg,
                        1.0f / qq.s, qq.z, qmn, qmx, &sqi);
  const size_t rbase = ((size_t)(b*W + i0 + irow) * NH + h) * DH;
  int Jm = __float_as_int(ctx[rbase]);
  const float tmxf = fminf(fmaxf(rintf((float)Jm * rf) + zs, qmn), qmx);
  const float iZ = 1.0f / ctx[rbase + 1];
  const char* kb = k8 + ((size_t)bh << 16);
  const int* skb = Sk8 + (bh << 10);
  const char* vb = v8 + ((size_t)bh << 16);

  int rA = 0;
  v4i accPV[4];
  #pragma unroll
  for (int tj = 0; tj < 4; ++tj){ v4i zz = {0,0,0,0}; accPV[tj] = zz; }

  for (int cc = 0; cc < 16; ++cc){
    #pragma unroll
    for (int jt = 0; jt < 4; ++jt){
      v4i Ak = *(const v4i*)(kb + (((size_t)((cc << 6) + (jt << 4) + lr)) << 6) + (lg << 4));
      v4i s4 = *(const v4i*)(skb + (cc << 6) + (jt << 4) + (lg << 2));
      v4i zz = {0, 0, 0, 0};
      v4i acc = __builtin_amdgcn_mfma_i32_16x16x64_i8(Ak, Bq, zz, 0, 0, 0);
      int J0 = acc[0] - izq * s4[0] - izk * sqi + c64;
      int J1 = acc[1] - izq * s4[1] - izk * sqi + c64;
      int J2 = acc[2] - izq * s4[2] - izk * sqi + c64;
      int J3 = acc[3] - izq * s4[3] - izk * sqi + c64;
      float tl0 = fminf(fmaxf(rintf((float)J0 * rf) + zs, qmn), qmx);
      float tl1 = fminf(fmaxf(rintf((float)J1 * rf) + zs, qmn), qmx);
      float tl2 = fminf(fmaxf(rintf((float)J2 * rf) + zs, qmn), qmx);
      float tl3 = fminf(fmaxf(rintf((float)J3 * rf) + zs, qmn), qmx);
      float p0 = exp2f((tl0 - tmxf) * c2) * iZ;
      float p1 = exp2f((tl1 - tmxf) * c2) * iZ;
      float p2 = exp2f((tl2 - tmxf) * c2) * iZ;
      float p3 = exp2f((tl3 - tmxf) * c2) * iZ;
      float a0 = fminf(fmaxf(rintf(p0 * inv_sa) + za, qmn), qmx);
      float a1 = fminf(fmaxf(rintf(p1 * inv_sa) + za, qmn), qmx);
      float a2 = fminf(fmaxf(rintf(p2 * inv_sa) + za, qmn), qmx);
      float a3 = fminf(fmaxf(rintf(p3 * inv_sa) + za, qmn), qmx);
      float4 y;
      y.x = (a0 - za) * sa; y.y = (a1 - za) * sa;
      y.z = (a2 - za) * sa; y.w = (a3 - za) * sa;
      *(float4*)(att + ((size_t)bh << 20) + (size_t)(i0 + irow) * W
                 + (cc << 6) + (jt << 4) + (lg << 2)) = y;
      int q0 = (int)a0, q1 = (int)a1, q2 = (int)a2, q3 = (int)a3;
      rA += q0 + q1 + q2 + q3;
      *(unsigned*)&As[irow][(jt << 4) + (lg << 2)] = pack4(q0, q1, q2, q3);
    }
    // As rows written & read by the SAME wave (in-order LDS) -> no barrier
    {
      v4i A2 = *(const v4i*)&As[(w << 4) + lr][lg << 4];
      #pragma unroll
      for (int tj = 0; tj < 4; ++tj){
        v4i B2 = *(const v4i*)(vb + (((size_t)((tj << 4) + lr)) << 10) + (cc << 6) + (lg << 4));
        accPV[tj] = __builtin_amdgcn_mfma_i32_16x16x64_i8(A2, B2, accPV[tj], 0, 0, 0);
      }
    }
  }

  rA += __shfl_xor(rA, 16);
  rA += __shfl_xor(rA, 32);
  if (lg == 0) RowA[irow] = rA;     // same-wave LDS write->read below

  const float sav = sa * vp.s;
  float lmin = 0.f, lmax = 0.f;
  #pragma unroll
  for (int tj = 0; tj < 4; ++tj){
    const int d = (tj << 4) + lr;
    const int cvd = Sv8[(bh << 6) + d];
    #pragma unroll
    for (int r = 0; r < 4; ++r){
      const int i = (w << 4) + (lg << 2) + r;
      int Jv = accPV[tj][r] - iza * cvd - izv * RowA[i] + 1024 * iza * izv;
      float c = sav * (float)Jv;
      lmin = fminf(lmin, c); lmax = fmaxf(lmax, c);
      ctx[(((size_t)(b * W + i0 + i)) * NH + h) * DH + d] = c;
    }
  }
  const int idx = (it + bh * 16) & (NS - 1);
  blk_minmax_atomic(lmin, lmax, slot_min(slots, 5) + idx, slot_max(slots, 5) + idx);
}

// ===== plain path (round-8 structure, no ws blobs) =====

__global__ __launch_bounds__(256) void pass1_plain(const float* __restrict__ qg,
                                                   const float* __restrict__ kg,
                                                   const unsigned* __restrict__ slots,
                                                   const int* __restrict__ bits_p,
                                                   float* __restrict__ stash,
                                                   int* __restrict__ jmn,
                                                   int* __restrict__ jmx){
  __shared__ __align__(16) signed char Qs[64][80], Ks[64][80];
  __shared__ int Sq[64], Sk[64];
  const int bits = *bits_p;
  const float qmx = (float)((1 << (bits-1)) - 1), qmn = -(float)(1 << (bits-1));
  const QP qq = qp_generic(slots, 0, qmn, qmx);
  const QP kp = qp_generic(slots, 1, qmn, qmx);
  const int it = blockIdx.x, bh = blockIdx.y, b = bh >> 3, h = bh & 7;
  const int i0 = it << 6, t = threadIdx.x;
  const int lane = t & 63, w = t >> 6, lr = lane & 15, lg = lane >> 4;
  const float isq = 1.0f / qq.s, isk = 1.0f / kp.s;
  const int izq = (int)qq.z, izk = (int)kp.z, c64 = 64 * izq * izk;

  stage_tile(qg + ((size_t)(b*W + i0) * NH + h) * DH, Qs, Sq, isq, qq.z, qmn, qmx, t);
  __syncthreads();
  const v4i Bq = *(const v4i*)&Qs[(w << 4) + lr][lg << 4];
  const int sqi = Sq[(w << 4) + lr];

  int gmin = 0x7fffffff, gmax = (int)0x80000000, rmax = (int)0x80000000;
  for (int cc = 0; cc < 16; ++cc){
    __syncthreads();
    stage_tile(kg + ((size_t)(b*W + (cc << 6)) * NH + h) * DH, Ks, Sk, isk, kp.z, qmn, qmx, t);
    __syncthreads();
    #pragma unroll
    for (int jt = 0; jt < 4; ++jt){
      v4i Ak = *(const v4i*)&Ks[(jt << 4) + lr][lg << 4];
      v4i zz = {0, 0, 0, 0};
      v4i acc = __builtin_amdgcn_mfma_i32_16x16x64_i8(Ak, Bq, zz, 0, 0, 0);
      v4i s4 = *(const v4i*)&Sk[(jt << 4) + (lg << 2)];
      #pragma unroll
      for (int r = 0; r < 4; ++r){
        int J = acc[r] - izq * s4[r] - izk * sqi + c64;
        gmin = min(gmin, J); gmax = max(gmax, J); rmax = max(rmax, J);
      }
    }
  }
  rmax = max(rmax, __shfl_xor(rmax, 16));
  rmax = max(rmax, __shfl_xor(rmax, 32));
  if (lg == 0)
    stash[((size_t)(b*W + i0 + (w << 4) + lr) * NH + h) * DH] = __int_as_float(rmax);
  const int idx = (it + bh * 16) & (NS - 1);
  blk_iminmax_atomic(gmin, gmax, jmn + idx, jmx + idx);
}

__global__ __launch_bounds__(256) void pass2_plain(const float* __restrict__ qg,
                                                   const float* __restrict__ kg,
                                                   unsigned* __restrict__ slots,
                                                   const int* __restrict__ jmn,
                                                   const int* __restrict__ jmx,
                                                   const int* __restrict__ bits_p,
                                                   float* __restrict__ stash){
  __shared__ __align__(16) signed char Qs[64][80], Ks[64][80];
  __shared__ int Sq[64], Sk[64];
  const int bits = *bits_p;
  const float qmx = (float)((1 << (bits-1)) - 1), qmn = -(float)(1 << (bits-1));
  const QP qq = qp_generic(slots, 0, qmn, qmx);
  const QP kp = qp_generic(slots, 1, qmn, qmx);
  const QP sp = qp_scores(jmn, jmx, qq.s, kp.s, qmn, qmx);
  const int it = blockIdx.x, bh = blockIdx.y, b = bh >> 3, h = bh & 7;
  const int i0 = it << 6, t = threadIdx.x;
  const int lane = t & 63, w = t >> 6, lr = lane & 15, lg = lane >> 4;
  const float isq = 1.0f / qq.s, isk = 1.0f / kp.s;
  const int izq = (int)qq.z, izk = (int)kp.z, c64 = 64 * izq * izk;
  const float rf = (0.125f * (qq.s * kp.s)) / sp.s;
  const float c2 = sp.s * L2E, zs = sp.z;
  const int irow = (w << 4) + lr;

  stage_tile(qg + ((size_t)(b*W + i0) * NH + h) * DH, Qs, Sq, isq, qq.z, qmn, qmx, t);
  __syncthreads();
  const v4i Bq = *(const v4i*)&Qs[irow][lg << 4];
  const int sqi = Sq[irow];
  int Jm = __float_as_int(stash[((size_t)(b*W + i0 + irow) * NH + h) * DH]);
  const float tmxf = fminf(fmaxf(rintf((float)Jm * rf) + zs, qmn), qmx);

  float zacc = 0.f;
  for (int cc = 0; cc < 16; ++cc){
    __syncthreads();
    stage_tile(kg + ((size_t)(b*W + (cc << 6)) * NH + h) * DH, Ks, Sk, isk, kp.z, qmn, qmx, t);
    __syncthreads();
    #pragma unroll
    for (int jt = 0; jt < 4; ++jt){
      v4i Ak = *(const v4i*)&Ks[(jt << 4) + lr][lg << 4];
      v4i zz = {0, 0, 0, 0};
      v4i acc = __builtin_amdgcn_mfma_i32_16x16x64_i8(Ak, Bq, zz, 0, 0, 0);
      v4i s4 = *(const v4i*)&Sk[(jt << 4) + (lg << 2)];
      int J0 = acc[0] - izq * s4[0] - izk * sqi + c64;
      int J1 = acc[1] - izq * s4[1] - izk * sqi + c64;
      int J2 = acc[2] - izq * s4[2] - izk * sqi + c64;
      int J3 = acc[3] - izq * s4[3] - izk * sqi + c64;
      float tl0 = fminf(fmaxf(rintf((float)J0 * rf) + zs, qmn), qmx);
      float tl1 = fminf(fmaxf(rintf((float)J1 * rf) + zs, qmn), qmx);
      float tl2 = fminf(fmaxf(rintf((float)J2 * rf) + zs, qmn), qmx);
      float tl3 = fminf(fmaxf(rintf((float)J3 * rf) + zs, qmn), qmx);
      zacc += exp2f((tl0 - tmxf) * c2);
      zacc += exp2f((tl1 - tmxf) * c2);
      zacc += exp2f((tl2 - tmxf) * c2);
      zacc += exp2f((tl3 - tmxf) * c2);
    }
  }
  zacc += __shfl_xor(zacc, 16);
  zacc += __shfl_xor(zacc, 32);
  if (lg == 0)
    stash[((size_t)(b*W + i0 + irow) * NH + h) * DH + 1] = zacc;
  float ratt = 1.0f / zacc;
  #pragma unroll
  for (int o = 1; o < 16; o <<= 1) ratt = fmaxf(ratt, __shfl_xor(ratt, o));
  if (lane == 0){
    const int idx = ((it << 2) + w + bh * 64) & (NS - 1);
    atomicMax(slot_max(slots, 4) + idx, enc_f(ratt));
  }
}

__global__ __launch_bounds__(256) void pass3_plain(const float* __restrict__ qg,
                                                   const float* __restrict__ kg,
                                                   const float* __restrict__ vg,
                                                   float* __restrict__ att,
                                                   float* __restrict__ ctx,
                                                   unsigned* __restrict__ slots,
                                                   const int* __restrict__ jmn,
                                                   const int* __restrict__ jmx,
                                                   const int* __restrict__ bits_p){
  __shared__ __align__(16) signed char Qs[64][80], Ks[64][80], Vs[64][80], As[64][80];
  __shared__ int Sq[64], Sk[64];
  __shared__ int RowA[64], ColV[64];
  const int bits = *bits_p;
  const float qmx = (float)((1 << (bits-1)) - 1), qmn = -(float)(1 << (bits-1));
  const QP qq = qp_generic(slots, 0, qmn, qmx);
  const QP kp = qp_generic(slots, 1, qmn, qmx);
  const QP sp = qp_scores(jmn, jmx, qq.s, kp.s, qmn, qmx);
  const QP vp = qp_generic(slots, 2, qmn, qmx);
  const QP ap = qp_generic(slots, 4, qmn, qmx);
  const int it = blockIdx.x, bh = blockIdx.y, b = bh >> 3, h = bh & 7;
  const int i0 = it << 6, t = threadIdx.x;
  const int lane = t & 63, w = t >> 6, lr = lane & 15, lg = lane >> 4;
  const float isq = 1.0f / qq.s, isk = 1.0f / kp.s;
  const int izq = (int)qq.z, izk = (int)kp.z, c64 = 64 * izq * izk;
  const float rf = (0.125f * (qq.s * kp.s)) / sp.s;
  const float c2 = sp.s * L2E, zs = sp.z;
  const float sa = ap.s, za = ap.z, inv_sa = 1.0f / sa;
  const float sv = vp.s, zv = vp.z, isv = 1.0f / sv;
  const int iza = (int)za, izv = (int)zv;
  const int irow = (w << 4) + lr;

  if (t < 64) ColV[t] = 0;
  stage_tile(qg + ((size_t)(b*W + i0) * NH + h) * DH, Qs, Sq, isq, qq.z, qmn, qmx, t);
  __syncthreads();
  const v4i Bq = *(const v4i*)&Qs[irow][lg << 4];
  const int sqi = Sq[irow];
  const size_t rbase = ((size_t)(b*W + i0 + irow) * NH + h) * DH;
  int Jm = __float_as_int(ctx[rbase]);
  const float tmxf = fminf(fmaxf(rintf((float)Jm * rf) + zs, qmn), qmx);
  const float iZ = 1.0f / ctx[rbase + 1];

  const int dq4 = (t & 15) << 2;
  const int kb  = (t >> 4) << 2;
  int cv4[4] = {0, 0, 0, 0};
  int rA = 0;
  v4i accPV[4];
  #pragma unroll
  for (int tj = 0; tj < 4; ++tj){ v4i zz = {0,0,0,0}; accPV[tj] = zz; }

  for (int cc = 0; cc < 16; ++cc){
    __syncthreads();
    stage_tile(kg + ((size_t)(b*W + (cc << 6)) * NH + h) * DH, Ks, Sk, isk, kp.z, qmn, qmx, t);
    {
      const float* vp_ = vg + ((size_t)(b*W + (cc << 6) + kb) * NH + h) * DH + dq4;
      float4 x0 = *(const float4*)(vp_);
      float4 x1 = *(const float4*)(vp_ + ROWF);
      float4 x2 = *(const float4*)(vp_ + 2 * ROWF);
      float4 x3 = *(const float4*)(vp_ + 3 * ROWF);
      int q00 = qint_m(x0.x, isv, zv, qmn, qmx), q01 = qint_m(x0.y, isv, zv, qmn, qmx),
          q02 = qint_m(x0.z, isv, zv, qmn, qmx), q03 = qint_m(x0.w, isv, zv, qmn, qmx);
      int q10 = qint_m(x1.x, isv, zv, qmn, qmx), q11 = qint_m(x1.y, isv, zv, qmn, qmx),
          q12 = qint_m(x1.z, isv, zv, qmn, qmx), q13 = qint_m(x1.w, isv, zv, qmn, qmx);
      int q20 = qint_m(x2.x, isv, zv, qmn, qmx), q21 = qint_m(x2.y, isv, zv, qmn, qmx),
          q22 = qint_m(x2.z, isv, zv, qmn, qmx), q23 = qint_m(x2.w, isv, zv, qmn, qmx);
      int q30 = qint_m(x3.x, isv, zv, qmn, qmx), q31 = qint_m(x3.y, isv, zv, qmn, qmx),
          q32 = qint_m(x3.z, isv, zv, qmn, qmx), q33 = qint_m(x3.w, isv, zv, qmn, qmx);
      cv4[0] += q00 + q10 + q20 + q30;
      cv4[1] += q01 + q11 + q21 + q31;
      cv4[2] += q02 + q12 + q22 + q32;
      cv4[3] += q03 + q13 + q23 + q33;
      *(unsigned*)&Vs[dq4 + 0][kb] = pack4(q00, q10, q20, q30);
      *(unsigned*)&Vs[dq4 + 1][kb] = pack4(q01, q11, q21, q31);
      *(unsigned*)&Vs[dq4 + 2][kb] = pack4(q02, q12, q22, q32);
      *(unsigned*)&Vs[dq4 + 3][kb] = pack4(q03, q13, q23, q33);
    }
    __syncthreads();
    #pragma unroll
    for (int jt = 0; jt < 4; ++jt){
      v4i Ak = *(const v4i*)&Ks[(jt << 4) + lr][lg << 4];
      v4i zz = {0, 0, 0, 0};
      v4i acc = __builtin_amdgcn_mfma_i32_16x16x64_i8(Ak, Bq, zz, 0, 0, 0);
      v4i s4 = *(const v4i*)&Sk[(jt << 4) + (lg << 2)];
      int J0 = acc[0] - izq * s4[0] - izk * sqi + c64;
      int J1 = acc[1] - izq * s4[1] - izk * sqi + c64;
      int J2 = acc[2] - izq * s4[2] - izk * sqi + c64;
      int J3 = acc[3] - izq * s4[3] - izk * sqi + c64;
      float tl0 = fminf(fmaxf(rintf((float)J0 * rf) + zs, qmn), qmx);
      float tl1 = fminf(fmaxf(rintf((float)J1 * rf) + zs, qmn), qmx);
      float tl2 = fminf(fmaxf(rintf((float)J2 * rf) + zs, qmn), qmx);
      float tl3 = fminf(fmaxf(rintf((float)J3 * rf) + zs, qmn), qmx);
      float p0 = exp2f((tl0 - tmxf) * c2) * iZ;
      float p1 = exp2f((tl1 - tmxf) * c2) * iZ;
      float p2 = exp2f((tl2 - tmxf) * c2) * iZ;
      float p3 = exp2f((tl3 - tmxf) * c2) * iZ;
      float a0 = fminf(fmaxf(rintf(p0 * inv_sa) + za, qmn), qmx);
      float a1 = fminf(fmaxf(rintf(p1 * inv_sa) + za, qmn), qmx);
      float a2 = fminf(fmaxf(rintf(p2 * inv_sa) + za, qmn), qmx);
      float a3 = fminf(fmaxf(rintf(p3 * inv_sa) + za, qmn), qmx);
      float4 y;
      y.x = (a0 - za) * sa; y.y = (a1 - za) * sa;
      y.z = (a2 - za) * sa; y.w = (a3 - za) * sa;
      *(float4*)(att + ((size_t)bh << 20) + (size_t)(i0 + irow) * W
                 + (cc << 6) + (jt << 4) + (lg << 2)) = y;
      int q0 = (int)a0, q1 = (int)a1, q2 = (int)a2, q3 = (int)a3;
      rA += q0 + q1 + q2 + q3;
      *(unsigned*)&As[irow][(jt << 4) + (lg << 2)] = pack4(q0, q1, q2, q3);
    }
    {
      v4i A2 = *(const v4i*)&As[(w << 4) + lr][lg << 4];
      #pragma unroll
      for (int tj = 0; tj < 4; ++tj){
        v4i B2 = *(const v4i*)&Vs[(tj << 4) + lr][lg << 4];
        accPV[tj] = __builtin_amdgcn_mfma_i32_16x16x64_i8(A2, B2, accPV[tj], 0, 0, 0);
      }
    }
  }

  rA += __shfl_xor(rA, 16);
  rA += __shfl_xor(rA, 32);
  if (lg == 0) RowA[irow] = rA;
  #pragma unroll
  for (int j = 0; j < 4; ++j) atomicAdd(&ColV[dq4 + j], cv4[j]);
  __syncthreads();

  const float sav = sa * sv;
  float lmin = 0.f, lmax = 0.f;
  #pragma unroll
  for (int tj = 0; tj < 4; ++tj){
    const int d = (tj << 4) + lr;
    #pragma unroll
    for (int r = 0; r < 4; ++r){
      const int i = (w << 4) + (lg << 2) + r;
      int Jv = accPV[tj][r] - iza * ColV[d] - izv * RowA[i] + 1024 * iza * izv;
      float c = sav * (float)Jv;
      lmin = fminf(lmin, c); lmax = fmaxf(lmax, c);
      ctx[(((size_t)(b * W + i0 + i)) * NH + h) * DH + d] = c;
    }
  }
  const int idx = (it + bh * 16) & (NS - 1);
  blk_minmax_atomic(lmin, lmax, slot_min(slots, 5) + idx, slot_max(slots, 5) + idx);
}

__global__ __launch_bounds__(256) void quantctx_kernel(float* __restrict__ ctx,
                                                       const unsigned* __restrict__ slots,
                                                       const int* __restrict__ bits_p){
  const int bits = *bits_p;
  const float qmx = (float)((1 << (bits-1)) - 1), qmn = -(float)(1 << (bits-1));
  const QP cp = qp_generic(slots, 5, qmn, qmx);
  size_t i = (size_t)blockIdx.x * blockDim.x + threadIdx.x;
  float4* p = (float4*)ctx;
  float4 x = p[i];
  x.x = fq1(x.x, cp.s, cp.z, qmn, qmx);
  x.y = fq1(x.y, cp.s, cp.z, qmn, qmx);
  x.z = fq1(x.z, cp.s, cp.z, qmn, qmx);
  x.w = fq1(x.w, cp.s, cp.z, qmn, qmx);
  p[i] = x;
}

// ---------- launch ----------

extern "C" void kernel_launch(void* const* d_in, const int* in_sizes, int n_in,
                              void* d_out, int out_size, void* d_ws, size_t ws_size,
                              hipStream_t stream){
  const float* q = (const float*)d_in[0];
  const float* k = (const float*)d_in[1];
  const float* v = (const float*)d_in[2];
  const int* bits = (const int*)d_in[3];
  float* ctx = (float*)d_out;                      // hosts per-row {Jmax,Z} stash (d=0,1)
  float* att = (float*)d_out + CTX_ELEMS;          // att_q output (written once, in pass3)
  unsigned* slots = (unsigned*)d_ws;               // [0, 3072)
  int* jmn = (int*)((char*)d_ws + 3072);           // 256 B
  int* jmx = (int*)((char*)d_ws + 3328);           // 256 B
  int* Sv8 = (int*)((char*)d_ws + 4096);           // 16 KB  -> [4096, 20480)
  int* Sk8 = (int*)((char*)d_ws + 20480);          // 256 KB -> [20480, 282624)
  char* k8 = (char*)d_ws + 282624;                 // 4 MB   -> [282624, 4476928)
  char* v8 = (char*)d_ws + 4476928;                // 4 MB   -> [4476928, 8671232)
  const bool cached = ws_size >= (size_t)8671232;

  hipLaunchKernelGGL(init_slots_kernel, dim3(1), dim3(256), 0, stream, slots, jmn, jmx, Sv8);
  hipLaunchKernelGGL(minmax3_kernel, dim3(512, 3), dim3(256), 0, stream, q, k, v, slots);
  if (cached){
    hipLaunchKernelGGL(pass1a_kernel, dim3(16, BHN), dim3(256), 0, stream,
                       k, v, slots, bits, k8, Sk8, v8, Sv8);
    hipLaunchKernelGGL(pass1b_kernel, dim3(16, BHN), dim3(256), 0, stream,
                       q, slots, bits, ctx, jmn, jmx, k8, Sk8);
    hipLaunchKernelGGL(pass2c_kernel, dim3(16, BHN), dim3(256), 0, stream,
                       q, slots, jmn, jmx, bits, ctx, k8, Sk8);
    hipLaunchKernelGGL(pass3c_kernel, dim3(16, BHN), dim3(256), 0, stream,
                       q, att, ctx, slots, jmn, jmx, bits, k8, Sk8, v8, Sv8);
  } else {
    hipLaunchKernelGGL(pass1_plain, dim3(16, BHN), dim3(256), 0, stream,
                       q, k, slots, bits, ctx, jmn, jmx);
    hipLaunchKernelGGL(pass2_plain, dim3(16, BHN), dim3(256), 0, stream,
                       q, k, slots, jmn, jmx, bits, ctx);
    hipLaunchKernelGGL(pass3_plain, dim3(16, BHN), dim3(256), 0, stream,
                       q, k, v, att, ctx, slots, jmn, jmx, bits);
  }
  hipLaunchKernelGGL(quantctx_kernel, dim3(4096), dim3(256), 0, stream, ctx, slots, bits);
}